// Round 5
// baseline (1395.826 us; speedup 1.0000x reference)
//
#include <hip/hip_runtime.h>
#include <hip/hip_cooperative_groups.h>
#include <hip/hip_bf16.h>

namespace cg = cooperative_groups;

#define NT 8192   // total nodes (2 graphs)
#define NN 4096   // nodes per graph
#define CD 128    // channels
#define NE 65536  // edges per graph

typedef __attribute__((ext_vector_type(8))) short bf16x8;
typedef __attribute__((ext_vector_type(16))) float f32x16;
typedef __attribute__((ext_vector_type(4))) float f32x4;

// ================= setup: concat + transposes + params + CSR build =================
struct SetupArgs {
  const float *x1, *x2;
  const int *ei1, *ei2;
  const float *W1, *W2, *WL;
  float *X, *WT1, *WT2, *WTL;
  const float *wlw0, *wlb0, *wrw0, *wrb0, *al0, *ar0;
  const float *wlw1, *wlb1, *wrw1, *wrb1, *al1, *ar1;
  float *VP;
  int *DEG, *OFFS, *CURS, *ADJ;
};

__global__ __launch_bounds__(256, 2) void k_setup(SetupArgs a) {
  cg::grid_group grid = cg::this_grid();
  __shared__ int part[256];
  int b = blockIdx.x, tid = threadIdx.x;
  int gid = b * 256 + tid;  // 0..131071
  // ---- p0: X concat (f32x4), weight transposes, attention params, DEG zero
  {
    const f32x4* s1 = (const f32x4*)a.x1;
    const f32x4* s2 = (const f32x4*)a.x2;
    f32x4* d = (f32x4*)a.X;
    d[gid] = s1[gid];
    d[gid + NN * CD / 4] = s2[gid];
  }
  if (gid < 81920) {
    int idx = gid;
    if (idx < 32768) { int c = idx >> 8, k = idx & 255; a.WT1[k * 128 + c] = a.W1[idx]; }
    else if (idx < 65536) { int j = idx - 32768; int c = j >> 8, k = j & 255; a.WT2[k * 128 + c] = a.W2[j]; }
    else { int j = idx - 65536; int c = j >> 7, k = j & 127; a.WTL[k * 128 + c] = a.WL[j]; }
  }
  if ((b == 508 || b == 509) && tid < 128) {
    int L = b - 508;
    const float* wlw = L ? a.wlw1 : a.wlw0;
    const float* wlb = L ? a.wlb1 : a.wlb0;
    const float* wrw = L ? a.wrw1 : a.wrw0;
    const float* wrb = L ? a.wrb1 : a.wrb0;
    const float* alv = L ? a.al1 : a.al0;
    const float* arv = L ? a.ar1 : a.ar0;
    float* vp = a.VP + L * 258;
    int c = tid;
    float sl = 0.f, sr = 0.f;
    for (int h = 0; h < 128; ++h) {
      sl += wlw[h * 128 + c] * alv[h];
      sr += wrw[h * 128 + c] * arv[h];
    }
    vp[c] = sl;
    vp[128 + c] = sr;
    if (c < 2) {
      const float* bb = c ? wrb : wlb;
      const float* aa = c ? arv : alv;
      float s = 0.f;
      for (int h = 0; h < 128; ++h) s += bb[h] * aa[h];
      vp[256 + c] = s;
    }
  }
  if (gid < 2 * NN) a.DEG[gid] = 0;
  grid.sync();
  // ---- p1: degree count
  {
    int g = gid >> 16, e = gid & 65535;
    const int* src = g ? a.ei2 : a.ei1;
    atomicAdd(&a.DEG[g * NN + src[e]], 1);
  }
  grid.sync();
  // ---- p2: offsets scan (blocks 0,1)
  if (b < 2) {
    int g = b;
    int loc[16];
    int s = 0;
    #pragma unroll
    for (int i = 0; i < 16; ++i) { loc[i] = s; s += a.DEG[g * NN + tid * 16 + i]; }
    part[tid] = s;
    __syncthreads();
    for (int d = 1; d < 256; d <<= 1) {
      int v = part[tid];
      int o = (tid >= d) ? part[tid - d] : 0;
      __syncthreads();
      part[tid] = v + o;
      __syncthreads();
    }
    int excl = tid ? part[tid - 1] : 0;
    #pragma unroll
    for (int i = 0; i < 16; ++i) {
      int o = excl + loc[i];
      a.OFFS[g * (NN + 1) + tid * 16 + i] = o;
      a.CURS[g * NN + tid * 16 + i] = o;
    }
    if (tid == 255) a.OFFS[g * (NN + 1) + NN] = part[255];
  }
  grid.sync();
  // ---- p3: CSR fill
  {
    int g = gid >> 16, e = gid & 65535;
    const int* ei = g ? a.ei2 : a.ei1;
    int s = ei[e], dn = ei[NE + e];
    int pos = atomicAdd(&a.CURS[g * NN + s], 1);
    a.ADJ[g * NE + pos] = dn;
  }
}

// ================= one GAT layer, fully fused (cooperative) =================
struct LayerArgs {
  const float* X; float* XN;
  const float* VP;
  float *AL, *AR, *ARS, *OT;
  int *RANK, *PERM;
  float *P1, *P2, *CT1, *CT2, *OFF1, *OFF2, *Q1L, *Q2L, *QCT1, *QCT2, *QOF1, *QOF2;
  const int *OFFS, *ADJ;
  float* AGGR;
  const float *WT, *WB;
  int dolin;
  const float *WTL, *LINB;
  __hip_bfloat16* FBF;
};

__global__ __launch_bounds__(256, 2) void k_layer(LayerArgs a) {
  cg::grid_group grid = cg::this_grid();
  __shared__ float smem[4096];  // 16 KB, reused per phase
  int b = blockIdx.x, tid = threadIdx.x;
  int gid = b * 256 + tid;       // 0..131071
  int lane = tid & 63, wv = tid >> 6;
  int gwave = b * 4 + wv;        // 0..2047

  // ---- p0: a_l/a_r per row (wave-reduce) + RANK zero
  if (gid < NT) a.RANK[gid] = 0;
  for (int row = gwave; row < NT; row += 2048) {
    float x0 = a.X[row * 128 + lane], x1 = a.X[row * 128 + 64 + lane];
    float sl = x0 * a.VP[lane] + x1 * a.VP[64 + lane];
    float sr = x0 * a.VP[128 + lane] + x1 * a.VP[192 + lane];
    #pragma unroll
    for (int m = 1; m < 64; m <<= 1) {
      sl += __shfl_xor(sl, m, 64);
      sr += __shfl_xor(sr, m, 64);
    }
    if (lane == 0) { a.AL[row] = sl + a.VP[256]; a.AR[row] = sr + a.VP[257]; }
  }
  grid.sync();

  // ---- p1: rank via O(N^2) chunked count (16 subtiles of 512)
  {
    float* tile = smem;
    int sub = b >> 5;           // 0..15 (uniform per block)
    int base = sub * 512;
    for (int t = tid; t < 512; t += 256) tile[t] = a.AR[base + t];
    __syncthreads();
    int j = (b & 31) * 256 + tid;
    float aj = a.AR[j];
    int cnt = 0;
    #pragma unroll 8
    for (int u = 0; u < 512; ++u) {
      float a2 = tile[u];
      cnt += (a2 < aj || (a2 == aj && (base + u) < j)) ? 1 : 0;
    }
    atomicAdd(&a.RANK[j], cnt);
    __syncthreads();
  }
  grid.sync();

  // ---- p2: scatter permutation + sorted a_r
  if (gid < NT) { int r = a.RANK[gid]; a.PERM[r] = gid; a.ARS[r] = a.AR[gid]; }
  grid.sync();

  // ---- p3: per-chunk weighted prefix sums (blocks 0..127, chunk = b)
  if (b < 128) {
    int* pc = (int*)smem;
    float* w1 = smem + 64;
    float* w2 = smem + 128;
    if (tid < 64) {
      int r = b * 64 + tid;
      pc[tid] = a.PERM[r];
      float ar = a.ARS[r];
      w1[tid] = __expf(ar);
      w2[tid] = __expf(0.2f * ar);
    }
    __syncthreads();
    {
      int c = tid & 127;
      const float* W = (tid < 128) ? w1 : w2;
      float* P = (tid < 128) ? a.P1 : a.P2;
      float* CT = (tid < 128) ? a.CT1 : a.CT2;
      float acc = 0.f;
      #pragma unroll 4
      for (int t = 0; t < 64; ++t) {
        acc += W[t] * a.X[pc[t] * 128 + c];
        P[(b * 64 + t) * 128 + c] = acc;
      }
      CT[b * 128 + c] = acc;
    }
    if (tid < 2) {
      const float* W = tid ? w2 : w1;
      float* Q = tid ? a.Q2L : a.Q1L;
      float* QC = tid ? a.QCT2 : a.QCT1;
      float acc = 0.f;
      for (int t = 0; t < 64; ++t) { acc += W[t]; Q[b * 64 + t] = acc; }
      QC[b] = acc;
    }
  }
  grid.sync();

  // ---- p4: chunk-total prefix scan
  if (b == 0) {
    int c = tid & 127;
    const float* CT = (tid < 128) ? a.CT1 : a.CT2;
    float* OFF = (tid < 128) ? a.OFF1 : a.OFF2;
    float acc = 0.f;
    #pragma unroll 8
    for (int ch = 0; ch < 128; ++ch) { acc += CT[ch * 128 + c]; OFF[ch * 128 + c] = acc; }
  } else if (b == 1 && tid < 2) {
    const float* QC = tid ? a.QCT2 : a.QCT1;
    float* QO = tid ? a.QOF2 : a.QOF1;
    float acc = 0.f;
    for (int ch = 0; ch < 128; ++ch) { acc += QC[ch]; QO[ch] = acc; }
  }
  grid.sync();

  // ---- p5: combine — ot = x - softmax-weighted sum (factorized leaky-relu)
  for (int v = b; v < 4096; v += 512) {
    int row = v * 2 + (tid >> 7);
    int c = tid & 127;
    float ali = a.AL[row];
    float A1 = __expf(ali), A2 = __expf(0.2f * ali);
    float xv = -ali;
    int lo = 0, hi = NT;
    while (lo < hi) {
      int mid = (lo + hi) >> 1;
      if (a.ARS[mid] <= xv) lo = mid + 1; else hi = mid;
    }
    int bd = lo - 1;
    float p1 = 0.f, p2 = 0.f, q1 = 0.f, q2 = 0.f;
    if (bd >= 0) {
      int ch = bd >> 6;
      p1 = a.P1[bd * 128 + c] + (ch ? a.OFF1[(ch - 1) * 128 + c] : 0.f);
      p2 = a.P2[bd * 128 + c] + (ch ? a.OFF2[(ch - 1) * 128 + c] : 0.f);
      q1 = a.Q1L[bd] + (ch ? a.QOF1[ch - 1] : 0.f);
      q2 = a.Q2L[bd] + (ch ? a.QOF2[ch - 1] : 0.f);
    }
    float T1 = a.OFF1[127 * 128 + c];
    float QT1 = a.QOF1[127];
    float num = A1 * (T1 - p1) + A2 * p2;
    float den = A1 * (QT1 - q1) + A2 * q2;
    a.OT[row * 128 + c] = a.X[row * 128 + c] - num / den;
  }
  grid.sync();

  // ---- p6: CSR mean aggregation, 4 nodes per wave interleaved (ILP)
  {
    int c4 = lane & 31;
    const f32x4* srcp[4];
    const int* adjp[4];
    int beg[4], end[4];
    f32x4 acc[4];
    #pragma unroll
    for (int k = 0; k < 4; ++k) {
      int node = gwave + k * 2048;
      int gg = node >> 12, nn_ = node & (NN - 1);
      beg[k] = a.OFFS[gg * (NN + 1) + nn_];
      end[k] = a.OFFS[gg * (NN + 1) + nn_ + 1];
      srcp[k] = (const f32x4*)((lane < 32 ? a.X : a.OT) + (size_t)gg * NN * CD);
      adjp[k] = a.ADJ + gg * NE;
      acc[k] = srcp[k][nn_ * 32 + c4];
    }
    int maxd = 0;
    #pragma unroll
    for (int k = 0; k < 4; ++k) maxd = max(maxd, end[k] - beg[k]);
    for (int s = 0; s < maxd; ++s) {
      #pragma unroll
      for (int k = 0; k < 4; ++k) {
        if (beg[k] + s < end[k]) {
          int d = adjp[k][beg[k] + s];
          acc[k] += srcp[k][d * 32 + c4];
        }
      }
    }
    #pragma unroll
    for (int k = 0; k < 4; ++k) {
      int node = gwave + k * 2048;
      f32x4 r = acc[k] / (float)(end[k] - beg[k] + 1);
      ((f32x4*)a.AGGR)[(size_t)node * 64 + (lane < 32 ? c4 : 32 + c4)] = r;
    }
  }
  grid.sync();

  // ---- p7: update GEMM (relu(aggr) @ WT + b), 16 rows/block, LDS-staged A
  {
    float* sA = smem;  // 16 x 256
    int r0 = b * 16;
    for (int i = tid; i < 16 * 256; i += 256) sA[i] = fmaxf(a.AGGR[(size_t)r0 * 256 + i], 0.f);
    __syncthreads();
    int half = tid >> 7, c = tid & 127;
    int rb = half * 8;
    float acc[8];
    float bc = a.WB[c];
    #pragma unroll
    for (int i = 0; i < 8; ++i) acc[i] = bc;
    for (int k4 = 0; k4 < 64; ++k4) {
      float w0 = a.WT[(k4 * 4 + 0) * 128 + c];
      float w1v = a.WT[(k4 * 4 + 1) * 128 + c];
      float w2v = a.WT[(k4 * 4 + 2) * 128 + c];
      float w3 = a.WT[(k4 * 4 + 3) * 128 + c];
      #pragma unroll
      for (int i = 0; i < 8; ++i) {
        f32x4 av = *(const f32x4*)&sA[(rb + i) * 256 + k4 * 4];
        acc[i] += av[0] * w0 + av[1] * w1v + av[2] * w2v + av[3] * w3;
      }
    }
    #pragma unroll
    for (int i = 0; i < 8; ++i) a.XN[(r0 + rb + i) * 128 + c] = acc[i];
  }

  // ---- p8 (layer 1 only): lin GEMM -> bf16 F
  if (a.dolin) {
    grid.sync();
    float* sA = smem;  // 16 x 128
    int r0 = b * 16;
    for (int i = tid; i < 16 * 128; i += 256) sA[i] = a.XN[(size_t)r0 * 128 + i];
    __syncthreads();
    int half = tid >> 7, c = tid & 127;
    int rb = half * 8;
    float acc[8];
    float bc = a.LINB[c];
    #pragma unroll
    for (int i = 0; i < 8; ++i) acc[i] = bc;
    for (int k4 = 0; k4 < 32; ++k4) {
      float w0 = a.WTL[(k4 * 4 + 0) * 128 + c];
      float w1v = a.WTL[(k4 * 4 + 1) * 128 + c];
      float w2v = a.WTL[(k4 * 4 + 2) * 128 + c];
      float w3 = a.WTL[(k4 * 4 + 3) * 128 + c];
      #pragma unroll
      for (int i = 0; i < 8; ++i) {
        f32x4 av = *(const f32x4*)&sA[(rb + i) * 128 + k4 * 4];
        acc[i] += av[0] * w0 + av[1] * w1v + av[2] * w2v + av[3] * w3;
      }
    }
    #pragma unroll
    for (int i = 0; i < 8; ++i)
      a.FBF[(r0 + rb + i) * 128 + c] = __float2bfloat16(acc[i]);
  }
}

// ================= final: out = sigmoid(F F^T), F bf16 8192x128 =================
__device__ inline f32x16 zero16() {
  f32x16 v;
  #pragma unroll
  for (int i = 0; i < 16; ++i) v[i] = 0.f;
  return v;
}

__device__ inline void store_frag(float* __restrict__ out, const f32x16& a,
                                  int grow0, int gcol) {
  #pragma unroll
  for (int r = 0; r < 16; ++r) {
    int rloc = (r & 3) + 8 * (r >> 2);  // C/D: row=(reg&3)+8*(reg>>2)+4*(lane>>5)
    float v = a[r];
    out[(size_t)(grow0 + rloc) * 8192 + gcol] =
        __builtin_amdgcn_rcpf(1.f + __expf(-v));
  }
}

__global__ __launch_bounds__(256) void k_final(const unsigned short* __restrict__ F,
                                               float* __restrict__ out) {
  __shared__ unsigned short AT[128 * 128];
  __shared__ unsigned short BT[128 * 128];
  int cb = blockIdx.x, rb = blockIdx.y;
  int tid = threadIdx.x;
  #pragma unroll
  for (int q = 0; q < 8; ++q) {
    int idx = q * 256 + tid;
    int r = idx >> 4, ck = idx & 15;
    unsigned off = (unsigned)((r * 256 + ck * 16) ^ ((r & 7) << 4));
    uint4 va = *(const uint4*)(F + (size_t)(rb * 128 + r) * 128 + ck * 8);
    *(uint4*)((char*)AT + off) = va;
    uint4 vb = *(const uint4*)(F + (size_t)(cb * 128 + r) * 128 + ck * 8);
    *(uint4*)((char*)BT + off) = vb;
  }
  __syncthreads();
  int lane = tid & 63, w = tid >> 6;
  int wr = w >> 1, wc = w & 1;
  int l31 = lane & 31, kh = lane >> 5;
  int xorm = (l31 & 7) << 4;
  int rowA0 = wr * 64 + l31, rowA1 = rowA0 + 32;
  int rowB0 = wc * 64 + l31, rowB1 = rowB0 + 32;
  f32x16 a00 = zero16(), a01 = zero16(), a10 = zero16(), a11 = zero16();
  #pragma unroll
  for (int ks = 0; ks < 8; ++ks) {
    int kb = ks * 32 + kh * 16;
    bf16x8 av0 = *(const bf16x8*)((const char*)AT + ((rowA0 * 256 + kb) ^ xorm));
    bf16x8 av1 = *(const bf16x8*)((const char*)AT + ((rowA1 * 256 + kb) ^ xorm));
    bf16x8 bv0 = *(const bf16x8*)((const char*)BT + ((rowB0 * 256 + kb) ^ xorm));
    bf16x8 bv1 = *(const bf16x8*)((const char*)BT + ((rowB1 * 256 + kb) ^ xorm));
    a00 = __builtin_amdgcn_mfma_f32_32x32x16_bf16(av0, bv0, a00, 0, 0, 0);
    a01 = __builtin_amdgcn_mfma_f32_32x32x16_bf16(av0, bv1, a01, 0, 0, 0);
    a10 = __builtin_amdgcn_mfma_f32_32x32x16_bf16(av1, bv0, a10, 0, 0, 0);
    a11 = __builtin_amdgcn_mfma_f32_32x32x16_bf16(av1, bv1, a11, 0, 0, 0);
  }
  int grow = rb * 128 + wr * 64 + 4 * kh;
  int gcol = cb * 128 + wc * 64 + l31;
  store_frag(out, a00, grow, gcol);
  store_frag(out, a01, grow, gcol + 32);
  store_frag(out, a10, grow + 32, gcol);
  store_frag(out, a11, grow + 32, gcol + 32);
}

// ================= host =================
extern "C" void kernel_launch(void* const* d_in, const int* in_sizes, int n_in,
                              void* d_out, int out_size, void* d_ws, size_t ws_size,
                              hipStream_t stream) {
  (void)in_sizes; (void)n_in; (void)out_size; (void)ws_size;
  const float* x1 = (const float*)d_in[0];
  const float* x2 = (const float*)d_in[1];
  const int* ei1 = (const int*)d_in[2];
  const int* ei2 = (const int*)d_in[3];
  const float* wl_w[2] = {(const float*)d_in[4], (const float*)d_in[10]};
  const float* wl_b[2] = {(const float*)d_in[5], (const float*)d_in[11]};
  const float* wr_w[2] = {(const float*)d_in[6], (const float*)d_in[12]};
  const float* wr_b[2] = {(const float*)d_in[7], (const float*)d_in[13]};
  const float* alv[2] = {(const float*)d_in[8], (const float*)d_in[14]};
  const float* arv[2] = {(const float*)d_in[9], (const float*)d_in[15]};
  const float* ww_w[2] = {(const float*)d_in[16], (const float*)d_in[18]};
  const float* ww_b[2] = {(const float*)d_in[17], (const float*)d_in[19]};
  const float* lin_w = (const float*)d_in[20];
  const float* lin_b = (const float*)d_in[21];

  char* wp = (char*)d_ws;
  auto alloc = [&](size_t bytes) -> char* {
    char* p = wp;
    wp += (bytes + 255) & ~(size_t)255;
    return p;
  };
  float* XA = (float*)alloc((size_t)NT * CD * 4);
  float* XB = (float*)alloc((size_t)NT * CD * 4);
  float* OT = (float*)alloc((size_t)NT * CD * 4);
  float* P1 = (float*)alloc((size_t)NT * CD * 4);  // P1+P2 contiguous: AGGR aliases both (8MB)
  float* P2 = (float*)alloc((size_t)NT * CD * 4);
  float* AGGR = P1;
  float* CT1 = (float*)alloc(128 * 128 * 4);
  float* CT2 = (float*)alloc(128 * 128 * 4);
  float* OFF1 = (float*)alloc(128 * 128 * 4);
  float* OFF2 = (float*)alloc(128 * 128 * 4);
  float* AL = (float*)alloc(NT * 4);
  float* AR_ = (float*)alloc(NT * 4);
  float* ARS = (float*)alloc(NT * 4);
  float* Q1L = (float*)alloc(NT * 4);
  float* Q2L = (float*)alloc(NT * 4);
  float* QCT1 = (float*)alloc(128 * 4);
  float* QCT2 = (float*)alloc(128 * 4);
  float* QOF1 = (float*)alloc(128 * 4);
  float* QOF2 = (float*)alloc(128 * 4);
  float* VP = (float*)alloc(2 * 258 * 4);
  float* WT1 = (float*)alloc(256 * 128 * 4);
  float* WT2 = (float*)alloc(256 * 128 * 4);
  float* WTL = (float*)alloc(128 * 128 * 4);
  int* RANK = (int*)alloc(NT * 4);
  int* PERM = (int*)alloc(NT * 4);
  int* DEG = (int*)alloc(2 * NN * 4);
  int* OFFS = (int*)alloc(2 * (NN + 1) * 4);
  int* CURS = (int*)alloc(2 * NN * 4);
  int* ADJ = (int*)alloc(2 * NE * 4);
  __hip_bfloat16* FBF = (__hip_bfloat16*)OT;  // OT dead before lin phase writes FBF

  SetupArgs sa;
  sa.x1 = x1; sa.x2 = x2; sa.ei1 = ei1; sa.ei2 = ei2;
  sa.W1 = ww_w[0]; sa.W2 = ww_w[1]; sa.WL = lin_w;
  sa.X = XA; sa.WT1 = WT1; sa.WT2 = WT2; sa.WTL = WTL;
  sa.wlw0 = wl_w[0]; sa.wlb0 = wl_b[0]; sa.wrw0 = wr_w[0]; sa.wrb0 = wr_b[0];
  sa.al0 = alv[0]; sa.ar0 = arv[0];
  sa.wlw1 = wl_w[1]; sa.wlb1 = wl_b[1]; sa.wrw1 = wr_w[1]; sa.wrb1 = wr_b[1];
  sa.al1 = alv[1]; sa.ar1 = arv[1];
  sa.VP = VP; sa.DEG = DEG; sa.OFFS = OFFS; sa.CURS = CURS; sa.ADJ = ADJ;
  void* sp[1] = {&sa};
  (void)hipLaunchCooperativeKernel((const void*)k_setup, dim3(512), dim3(256), sp, 0, stream);

  float* X = XA;
  float* XN = XB;
  for (int L = 0; L < 2; ++L) {
    LayerArgs la;
    la.X = X; la.XN = XN; la.VP = VP + L * 258;
    la.AL = AL; la.AR = AR_; la.ARS = ARS; la.OT = OT;
    la.RANK = RANK; la.PERM = PERM;
    la.P1 = P1; la.P2 = P2; la.CT1 = CT1; la.CT2 = CT2;
    la.OFF1 = OFF1; la.OFF2 = OFF2;
    la.Q1L = Q1L; la.Q2L = Q2L; la.QCT1 = QCT1; la.QCT2 = QCT2;
    la.QOF1 = QOF1; la.QOF2 = QOF2;
    la.OFFS = OFFS; la.ADJ = ADJ; la.AGGR = AGGR;
    la.WT = L ? WT2 : WT1; la.WB = ww_b[L];
    la.dolin = (L == 1) ? 1 : 0;
    la.WTL = WTL; la.LINB = lin_b; la.FBF = FBF;
    void* lp[1] = {&la};
    (void)hipLaunchCooperativeKernel((const void*)k_layer, dim3(512), dim3(256), lp, 0, stream);
    float* t = X; X = XN; XN = t;
  }
  k_final<<<dim3(64, 64), 256, 0, stream>>>((const unsigned short*)FBF, (float*)d_out);
}

// Round 6
// 450.693 us; speedup vs baseline: 3.0971x; 3.0971x over previous
//
#include <hip/hip_runtime.h>
#include <hip/hip_bf16.h>

#define NT 8192   // total nodes (2 graphs)
#define NN 4096   // nodes per graph
#define CD 128    // channels
#define NE 65536  // edges per graph
#define SCOPE_AGT __HIP_MEMORY_SCOPE_AGENT

typedef __attribute__((ext_vector_type(8))) short bf16x8;
typedef __attribute__((ext_vector_type(16))) float f32x16;
typedef __attribute__((ext_vector_type(4))) float f32x4;

__device__ inline void stg_f(float* p, float v) {
  __hip_atomic_store(p, v, __ATOMIC_RELAXED, SCOPE_AGT);
}
__device__ inline float ldg_f(const float* p) {
  return __hip_atomic_load(p, __ATOMIC_RELAXED, SCOPE_AGT);
}
__device__ inline int ldg_i(const int* p) {
  return __hip_atomic_load(p, __ATOMIC_RELAXED, SCOPE_AGT);
}

// ---------------- prep: concat + transposes + params + zeros ----------------
__global__ __launch_bounds__(256) void k_prep(
    const float* __restrict__ x1, const float* __restrict__ x2, float* __restrict__ X,
    const float* __restrict__ W1, const float* __restrict__ W2, const float* __restrict__ WL,
    float* __restrict__ WT1, float* __restrict__ WT2, float* __restrict__ WTL,
    const float* __restrict__ wlw0, const float* __restrict__ wlb0,
    const float* __restrict__ wrw0, const float* __restrict__ wrb0,
    const float* __restrict__ al0, const float* __restrict__ ar0,
    const float* __restrict__ wlw1, const float* __restrict__ wlb1,
    const float* __restrict__ wrw1, const float* __restrict__ wrb1,
    const float* __restrict__ al1, const float* __restrict__ ar1,
    float* __restrict__ VP, int* __restrict__ DEG, int* __restrict__ TK) {
  int b = blockIdx.x, tid = threadIdx.x;
  int gid = b * 256 + tid;  // 0..131071
  {
    const f32x4* s1 = (const f32x4*)x1;
    const f32x4* s2 = (const f32x4*)x2;
    f32x4* d = (f32x4*)X;
    d[gid] = s1[gid];
    d[gid + NN * CD / 4] = s2[gid];
  }
  if (gid < 81920) {
    int idx = gid;
    if (idx < 32768) { int c = idx >> 8, k = idx & 255; WT1[k * 128 + c] = W1[idx]; }
    else if (idx < 65536) { int j = idx - 32768; int c = j >> 8, k = j & 255; WT2[k * 128 + c] = W2[j]; }
    else { int j = idx - 65536; int c = j >> 7, k = j & 127; WTL[k * 128 + c] = WL[j]; }
  }
  if ((b == 508 || b == 509) && tid < 128) {
    int L = b - 508;
    const float* wlw = L ? wlw1 : wlw0;
    const float* wlb = L ? wlb1 : wlb0;
    const float* wrw = L ? wrw1 : wrw0;
    const float* wrb = L ? wrb1 : wrb0;
    const float* alv = L ? al1 : al0;
    const float* arv = L ? ar1 : ar0;
    float* vp = VP + L * 258;
    int c = tid;
    float sl = 0.f, sr = 0.f;
    for (int h = 0; h < 128; ++h) {
      sl += wlw[h * 128 + c] * alv[h];
      sr += wrw[h * 128 + c] * arv[h];
    }
    vp[c] = sl;
    vp[128 + c] = sr;
    if (c < 2) {
      const float* bb = c ? wrb : wlb;
      const float* aa = c ? arv : alv;
      float s = 0.f;
      for (int h = 0; h < 128; ++h) s += bb[h] * aa[h];
      vp[256 + c] = s;
    }
  }
  if (gid < 2 * NN) DEG[gid] = 0;
  if (b == 0 && tid < 8) TK[tid] = 0;
}

// ---------------- shared device bodies ----------------
__device__ void alar_row(const float* __restrict__ X, const float* __restrict__ VP,
                         float* __restrict__ AL, float* __restrict__ AR,
                         int row, int lane) {
  float x0 = X[row * 128 + lane], x1 = X[row * 128 + 64 + lane];
  float sl = x0 * VP[lane] + x1 * VP[64 + lane];
  float sr = x0 * VP[128 + lane] + x1 * VP[192 + lane];
  #pragma unroll
  for (int m = 1; m < 64; m <<= 1) {
    sl += __shfl_xor(sl, m, 64);
    sr += __shfl_xor(sr, m, 64);
  }
  if (lane == 0) { AL[row] = sl + VP[256]; AR[row] = sr + VP[257]; }
}

// rank (O(N^2) chunked count) + perm scatter by last-arriving block (ticket)
__device__ void rankperm_body(int rb, int tid, const float* __restrict__ AR,
                              int* __restrict__ RANK, int* __restrict__ PERM,
                              float* __restrict__ ARS, int* __restrict__ TK, int slot) {
  __shared__ float tile[1024];
  __shared__ int isLast;
  int jb = rb & 31, tb = rb >> 5;
  int base = tb * 1024;
  for (int t = tid; t < 1024; t += 256) tile[t] = AR[base + t];
  __syncthreads();
  int j = jb * 256 + tid;
  float aj = AR[j];
  int cnt = 0;
  #pragma unroll 8
  for (int u = 0; u < 1024; ++u) {
    float a2 = tile[u];
    cnt += (a2 < aj || (a2 == aj && (base + u) < j)) ? 1 : 0;
  }
  atomicAdd(&RANK[j], cnt);
  __threadfence();
  __syncthreads();
  if (tid == 0) {
    int t = __hip_atomic_fetch_add(&TK[slot], 1, __ATOMIC_ACQ_REL, SCOPE_AGT);
    isLast = (t == 255);
  }
  __syncthreads();
  if (isLast) {
    for (int jj = tid; jj < NT; jj += 256) {
      int rk = ldg_i(&RANK[jj]);
      PERM[rk] = jj;
      ARS[rk] = AR[jj];
    }
  }
}

// per-chunk weighted prefix sums + chunk-total scan by last block (ticket)
__device__ void scanA_body(int chunk, int tid, const float* __restrict__ X,
                           const int* __restrict__ PERM, const float* __restrict__ ARS,
                           float* __restrict__ P1, float* __restrict__ P2,
                           float* __restrict__ CT1, float* __restrict__ CT2,
                           float* __restrict__ Q1L, float* __restrict__ Q2L,
                           float* __restrict__ QCT1, float* __restrict__ QCT2,
                           float* __restrict__ OFF1, float* __restrict__ OFF2,
                           float* __restrict__ QOF1, float* __restrict__ QOF2,
                           int* __restrict__ TK, int slot) {
  __shared__ float sm[192];
  __shared__ int isLast;
  int* pc = (int*)sm;
  float* w1 = sm + 64;
  float* w2 = sm + 128;
  if (tid < 64) {
    int r = chunk * 64 + tid;
    pc[tid] = PERM[r];
    float a = ARS[r];
    w1[tid] = __expf(a);
    w2[tid] = __expf(0.2f * a);
  }
  __syncthreads();
  int c = tid & 127;
  {
    const float* W = (tid < 128) ? w1 : w2;
    float* P = (tid < 128) ? P1 : P2;
    float* CT = (tid < 128) ? CT1 : CT2;
    float acc = 0.f;
    #pragma unroll 4
    for (int t = 0; t < 64; ++t) {
      acc += W[t] * X[pc[t] * 128 + c];
      P[(chunk * 64 + t) * 128 + c] = acc;
    }
    stg_f(&CT[chunk * 128 + c], acc);
  }
  if (tid < 2) {
    const float* Wq = tid ? w2 : w1;
    float* Q = tid ? Q2L : Q1L;
    float* QC = tid ? QCT2 : QCT1;
    float qa = 0.f;
    for (int t = 0; t < 64; ++t) { qa += Wq[t]; Q[chunk * 64 + t] = qa; }
    stg_f(&QC[chunk], qa);
  }
  __threadfence();
  __syncthreads();
  if (tid == 0) {
    int t = __hip_atomic_fetch_add(&TK[slot], 1, __ATOMIC_ACQ_REL, SCOPE_AGT);
    isLast = (t == 127);
  }
  __syncthreads();
  if (isLast) {
    const float* CTs = (tid < 128) ? CT1 : CT2;
    float* OFF = (tid < 128) ? OFF1 : OFF2;
    float a2 = 0.f;
    #pragma unroll 8
    for (int ch = 0; ch < 128; ++ch) { a2 += ldg_f(&CTs[ch * 128 + c]); OFF[ch * 128 + c] = a2; }
    if (tid < 2) {
      const float* QC = tid ? QCT2 : QCT1;
      float* QO = tid ? QOF2 : QOF1;
      float qa = 0.f;
      for (int ch = 0; ch < 128; ++ch) { qa += ldg_f(&QC[ch]); QO[ch] = qa; }
    }
  }
}

// ---------------- stage2: deg atomics || alar0 (+RANK zero) ----------------
__global__ __launch_bounds__(256) void k_stage2(
    const int* __restrict__ EI1, const int* __restrict__ EI2, int* __restrict__ DEG,
    const float* __restrict__ X, const float* __restrict__ VP0,
    float* __restrict__ AL, float* __restrict__ AR, int* __restrict__ RANK) {
  int b = blockIdx.x, tid = threadIdx.x;
  if (b < 512) {
    int gid = b * 256 + tid;
    int g = gid >> 16, e = gid & 65535;
    const int* src = g ? EI2 : EI1;
    atomicAdd(&DEG[g * NN + src[e]], 1);
  } else {
    int bb = b - 512;
    int gid = bb * 256 + tid;
    if (gid < NT) RANK[gid] = 0;
    alar_row(X, VP0, AL, AR, bb * 4 + (tid >> 6), tid & 63);
  }
}

// ---------------- stage3: scanoff || rank0+perm0 ----------------
__device__ void scanoff_body(int g, int tid, const int* __restrict__ DEG,
                             int* __restrict__ OFFS, int* __restrict__ CURS) {
  __shared__ int part[256];
  int loc[16];
  int s = 0;
  #pragma unroll
  for (int i = 0; i < 16; ++i) { loc[i] = s; s += DEG[g * NN + tid * 16 + i]; }
  part[tid] = s;
  __syncthreads();
  for (int d = 1; d < 256; d <<= 1) {
    int v = part[tid];
    int o = (tid >= d) ? part[tid - d] : 0;
    __syncthreads();
    part[tid] = v + o;
    __syncthreads();
  }
  int excl = tid ? part[tid - 1] : 0;
  #pragma unroll
  for (int i = 0; i < 16; ++i) {
    int o = excl + loc[i];
    OFFS[g * (NN + 1) + tid * 16 + i] = o;
    CURS[g * NN + tid * 16 + i] = o;
  }
  if (tid == 255) OFFS[g * (NN + 1) + NN] = part[255];
}

__global__ __launch_bounds__(256) void k_stage3(
    const int* __restrict__ DEG, int* __restrict__ OFFS, int* __restrict__ CURS,
    const float* __restrict__ AR, int* __restrict__ RANK, int* __restrict__ PERM,
    float* __restrict__ ARS, int* __restrict__ TK) {
  int b = blockIdx.x, tid = threadIdx.x;
  if (b < 2) scanoff_body(b, tid, DEG, OFFS, CURS);
  else rankperm_body(b - 2, tid, AR, RANK, PERM, ARS, TK, 0);
}

// ---------------- stage4: fill || scanA0(+scanB0) ----------------
__global__ __launch_bounds__(256) void k_stage4(
    const int* __restrict__ EI1, const int* __restrict__ EI2,
    int* __restrict__ CURS, int* __restrict__ ADJ,
    const float* __restrict__ X, const int* __restrict__ PERM, const float* __restrict__ ARS,
    float* __restrict__ P1, float* __restrict__ P2,
    float* __restrict__ CT1, float* __restrict__ CT2,
    float* __restrict__ Q1L, float* __restrict__ Q2L,
    float* __restrict__ QCT1, float* __restrict__ QCT2,
    float* __restrict__ OFF1, float* __restrict__ OFF2,
    float* __restrict__ QOF1, float* __restrict__ QOF2, int* __restrict__ TK) {
  int b = blockIdx.x, tid = threadIdx.x;
  if (b < 512) {
    int gid = b * 256 + tid;
    int g = gid >> 16, e = gid & 65535;
    const int* ei = g ? EI2 : EI1;
    int s = ei[e], dn = ei[NE + e];
    int pos = atomicAdd(&CURS[g * NN + s], 1);
    ADJ[g * NE + pos] = dn;
  } else {
    scanA_body(b - 512, tid, X, PERM, ARS, P1, P2, CT1, CT2, Q1L, Q2L,
               QCT1, QCT2, OFF1, OFF2, QOF1, QOF2, TK, 1);
  }
}

__global__ __launch_bounds__(256) void k_rankperm1(
    const float* __restrict__ AR, int* __restrict__ RANK, int* __restrict__ PERM,
    float* __restrict__ ARS, int* __restrict__ TK) {
  rankperm_body(blockIdx.x, threadIdx.x, AR, RANK, PERM, ARS, TK, 2);
}

__global__ __launch_bounds__(256) void k_scanA1(
    const float* __restrict__ X, const int* __restrict__ PERM, const float* __restrict__ ARS,
    float* __restrict__ P1, float* __restrict__ P2,
    float* __restrict__ CT1, float* __restrict__ CT2,
    float* __restrict__ Q1L, float* __restrict__ Q2L,
    float* __restrict__ QCT1, float* __restrict__ QCT2,
    float* __restrict__ OFF1, float* __restrict__ OFF2,
    float* __restrict__ QOF1, float* __restrict__ QOF2, int* __restrict__ TK) {
  scanA_body(blockIdx.x, threadIdx.x, X, PERM, ARS, P1, P2, CT1, CT2, Q1L, Q2L,
             QCT1, QCT2, OFF1, OFF2, QOF1, QOF2, TK, 3);
}

// ---------------- combine: ot = x - att-weighted mean (factorized) ----------------
__global__ void k_combine(const float* __restrict__ X, const float* __restrict__ AL,
                          const float* __restrict__ ARS,
                          const float* __restrict__ P1, const float* __restrict__ P2,
                          const float* __restrict__ OFF1, const float* __restrict__ OFF2,
                          const float* __restrict__ Q1L, const float* __restrict__ Q2L,
                          const float* __restrict__ QOF1, const float* __restrict__ QOF2,
                          float* __restrict__ OT) {
  int row = blockIdx.x * 2 + (threadIdx.x >> 7);
  int c = threadIdx.x & 127;
  float ali = AL[row];
  float A1 = __expf(ali), A2 = __expf(0.2f * ali);
  float xv = -ali;
  int lo = 0, hi = NT;
  while (lo < hi) {
    int mid = (lo + hi) >> 1;
    if (ARS[mid] <= xv) lo = mid + 1; else hi = mid;
  }
  int bd = lo - 1;
  float p1 = 0.f, p2 = 0.f, q1 = 0.f, q2 = 0.f;
  if (bd >= 0) {
    int ch = bd >> 6;
    p1 = P1[bd * 128 + c] + (ch ? OFF1[(ch - 1) * 128 + c] : 0.f);
    p2 = P2[bd * 128 + c] + (ch ? OFF2[(ch - 1) * 128 + c] : 0.f);
    q1 = Q1L[bd] + (ch ? QOF1[ch - 1] : 0.f);
    q2 = Q2L[bd] + (ch ? QOF2[ch - 1] : 0.f);
  }
  float T1 = OFF1[127 * 128 + c];
  float QT1 = QOF1[127];
  float num = A1 * (T1 - p1) + A2 * p2;
  float den = A1 * (QT1 - q1) + A2 * q2;
  OT[row * 128 + c] = X[row * 128 + c] - num / den;
}

// ---------------- aggr (CSR mean) + update GEMM fused; optional alar-next / lin ----------------
__global__ __launch_bounds__(256) void k_aggrgemm(
    const float* __restrict__ X, const float* __restrict__ OT,
    const int* __restrict__ OFFS, const int* __restrict__ ADJ,
    const float* __restrict__ WT, const float* __restrict__ WB, float* __restrict__ XN,
    int mode,  // 0: + alar(next layer) & RANK zero ; 1: + lin -> FBF
    const float* __restrict__ VP1, float* __restrict__ AL, float* __restrict__ AR,
    int* __restrict__ RANK,
    const float* __restrict__ WTL, const float* __restrict__ LINB,
    __hip_bfloat16* __restrict__ FBF) {
  __shared__ float sA[8 * 256];  // 8 KB
  int b = blockIdx.x, tid = threadIdx.x;
  int lane = tid & 63, wv = tid >> 6, c4 = lane & 31;
  if (mode == 0) {
    int gid = b * 256 + tid;
    if (gid < NT) RANK[gid] = 0;
  }
  // gather phase: 2 nodes per wave, interleaved
  {
    int beg[2], end[2];
    const f32x4* srcp[2];
    const int* adjp[2];
    f32x4 acc[2];
    #pragma unroll
    for (int k = 0; k < 2; ++k) {
      int node = b * 8 + wv * 2 + k;
      int g = node >> 12, n = node & (NN - 1);
      beg[k] = OFFS[g * (NN + 1) + n];
      end[k] = OFFS[g * (NN + 1) + n + 1];
      srcp[k] = (const f32x4*)((lane < 32 ? X : OT) + (size_t)g * NN * CD);
      adjp[k] = ADJ + g * NE;
      acc[k] = srcp[k][n * 32 + c4];
    }
    int maxd = max(end[0] - beg[0], end[1] - beg[1]);
    for (int s = 0; s < maxd; ++s) {
      #pragma unroll
      for (int k = 0; k < 2; ++k) {
        if (beg[k] + s < end[k]) acc[k] += srcp[k][adjp[k][beg[k] + s] * 32 + c4];
      }
    }
    #pragma unroll
    for (int k = 0; k < 2; ++k) {
      f32x4 r = acc[k] / (float)(end[k] - beg[k] + 1);
      #pragma unroll
      for (int q = 0; q < 4; ++q) r[q] = fmaxf(r[q], 0.f);
      *(f32x4*)&sA[(wv * 2 + k) * 256 + (lane < 32 ? c4 * 4 : 128 + c4 * 4)] = r;
    }
  }
  __syncthreads();
  // update GEMM: 8 rows x (256 -> 128)
  int c = tid & 127, half = tid >> 7;
  float accv[4];
  float bc = WB[c];
  #pragma unroll
  for (int i = 0; i < 4; ++i) accv[i] = bc;
  for (int k4 = 0; k4 < 64; ++k4) {
    float w0 = WT[(k4 * 4 + 0) * 128 + c];
    float w1v = WT[(k4 * 4 + 1) * 128 + c];
    float w2v = WT[(k4 * 4 + 2) * 128 + c];
    float w3 = WT[(k4 * 4 + 3) * 128 + c];
    #pragma unroll
    for (int i = 0; i < 4; ++i) {
      f32x4 av = *(const f32x4*)&sA[(half * 4 + i) * 256 + k4 * 4];
      accv[i] += av[0] * w0 + av[1] * w1v + av[2] * w2v + av[3] * w3;
    }
  }
  #pragma unroll
  for (int i = 0; i < 4; ++i) XN[(size_t)(b * 8 + half * 4 + i) * 128 + c] = accv[i];
  __syncthreads();
  float* sB = sA;  // overlay: 8 x 128
  #pragma unroll
  for (int i = 0; i < 4; ++i) sB[(half * 4 + i) * 128 + c] = accv[i];
  __syncthreads();
  if (mode == 0) {
    // next-layer a_l/a_r from LDS rows
    #pragma unroll
    for (int k = 0; k < 2; ++k) {
      int lr = wv * 2 + k;
      float x0 = sB[lr * 128 + lane], x1 = sB[lr * 128 + 64 + lane];
      float sl = x0 * VP1[lane] + x1 * VP1[64 + lane];
      float sr = x0 * VP1[128 + lane] + x1 * VP1[192 + lane];
      #pragma unroll
      for (int m = 1; m < 64; m <<= 1) {
        sl += __shfl_xor(sl, m, 64);
        sr += __shfl_xor(sr, m, 64);
      }
      if (lane == 0) { AL[b * 8 + lr] = sl + VP1[256]; AR[b * 8 + lr] = sr + VP1[257]; }
    }
  } else {
    // lin GEMM: 8 rows x (128 -> 128), bf16 out
    float acl[4];
    float lb = LINB[c];
    #pragma unroll
    for (int i = 0; i < 4; ++i) acl[i] = lb;
    for (int k4 = 0; k4 < 32; ++k4) {
      float w0 = WTL[(k4 * 4 + 0) * 128 + c];
      float w1v = WTL[(k4 * 4 + 1) * 128 + c];
      float w2v = WTL[(k4 * 4 + 2) * 128 + c];
      float w3 = WTL[(k4 * 4 + 3) * 128 + c];
      #pragma unroll
      for (int i = 0; i < 4; ++i) {
        f32x4 av = *(const f32x4*)&sB[(half * 4 + i) * 128 + k4 * 4];
        acl[i] += av[0] * w0 + av[1] * w1v + av[2] * w2v + av[3] * w3;
      }
    }
    #pragma unroll
    for (int i = 0; i < 4; ++i)
      FBF[(size_t)(b * 8 + half * 4 + i) * 128 + c] = __float2bfloat16(acl[i]);
  }
}

// ---------------- final: out = sigmoid(F F^T), F bf16 8192x128 ----------------
__device__ inline f32x16 zero16() {
  f32x16 v;
  #pragma unroll
  for (int i = 0; i < 16; ++i) v[i] = 0.f;
  return v;
}

__device__ inline void store_frag(float* __restrict__ out, const f32x16& a,
                                  int grow0, int gcol) {
  #pragma unroll
  for (int r = 0; r < 16; ++r) {
    int rloc = (r & 3) + 8 * (r >> 2);  // C/D: row=(reg&3)+8*(reg>>2)+4*(lane>>5)
    float v = a[r];
    out[(size_t)(grow0 + rloc) * 8192 + gcol] =
        __builtin_amdgcn_rcpf(1.f + __expf(-v));
  }
}

__global__ __launch_bounds__(256) void k_final(const unsigned short* __restrict__ F,
                                               float* __restrict__ out) {
  __shared__ unsigned short AT[128 * 128];
  __shared__ unsigned short BT[128 * 128];
  int cb = blockIdx.x, rb = blockIdx.y;
  int tid = threadIdx.x;
  #pragma unroll
  for (int q = 0; q < 8; ++q) {
    int idx = q * 256 + tid;
    int r = idx >> 4, ck = idx & 15;
    unsigned off = (unsigned)((r * 256 + ck * 16) ^ ((r & 7) << 4));
    uint4 va = *(const uint4*)(F + (size_t)(rb * 128 + r) * 128 + ck * 8);
    *(uint4*)((char*)AT + off) = va;
    uint4 vb = *(const uint4*)(F + (size_t)(cb * 128 + r) * 128 + ck * 8);
    *(uint4*)((char*)BT + off) = vb;
  }
  __syncthreads();
  int lane = tid & 63, w = tid >> 6;
  int wr = w >> 1, wc = w & 1;
  int l31 = lane & 31, kh = lane >> 5;
  int xorm = (l31 & 7) << 4;
  int rowA0 = wr * 64 + l31, rowA1 = rowA0 + 32;
  int rowB0 = wc * 64 + l31, rowB1 = rowB0 + 32;
  f32x16 a00 = zero16(), a01 = zero16(), a10 = zero16(), a11 = zero16();
  #pragma unroll
  for (int ks = 0; ks < 8; ++ks) {
    int kb = ks * 32 + kh * 16;
    bf16x8 av0 = *(const bf16x8*)((const char*)AT + ((rowA0 * 256 + kb) ^ xorm));
    bf16x8 av1 = *(const bf16x8*)((const char*)AT + ((rowA1 * 256 + kb) ^ xorm));
    bf16x8 bv0 = *(const bf16x8*)((const char*)BT + ((rowB0 * 256 + kb) ^ xorm));
    bf16x8 bv1 = *(const bf16x8*)((const char*)BT + ((rowB1 * 256 + kb) ^ xorm));
    a00 = __builtin_amdgcn_mfma_f32_32x32x16_bf16(av0, bv0, a00, 0, 0, 0);
    a01 = __builtin_amdgcn_mfma_f32_32x32x16_bf16(av0, bv1, a01, 0, 0, 0);
    a10 = __builtin_amdgcn_mfma_f32_32x32x16_bf16(av1, bv0, a10, 0, 0, 0);
    a11 = __builtin_amdgcn_mfma_f32_32x32x16_bf16(av1, bv1, a11, 0, 0, 0);
  }
  int grow = rb * 128 + wr * 64 + 4 * kh;
  int gcol = cb * 128 + wc * 64 + l31;
  store_frag(out, a00, grow, gcol);
  store_frag(out, a01, grow, gcol + 32);
  store_frag(out, a10, grow + 32, gcol);
  store_frag(out, a11, grow + 32, gcol + 32);
}

// ---------------- host ----------------
extern "C" void kernel_launch(void* const* d_in, const int* in_sizes, int n_in,
                              void* d_out, int out_size, void* d_ws, size_t ws_size,
                              hipStream_t stream) {
  (void)in_sizes; (void)n_in; (void)out_size; (void)ws_size;
  const float* x1 = (const float*)d_in[0];
  const float* x2 = (const float*)d_in[1];
  const int* ei1 = (const int*)d_in[2];
  const int* ei2 = (const int*)d_in[3];
  const float* wl_w[2] = {(const float*)d_in[4], (const float*)d_in[10]};
  const float* wl_b[2] = {(const float*)d_in[5], (const float*)d_in[11]};
  const float* wr_w[2] = {(const float*)d_in[6], (const float*)d_in[12]};
  const float* wr_b[2] = {(const float*)d_in[7], (const float*)d_in[13]};
  const float* alv[2] = {(const float*)d_in[8], (const float*)d_in[14]};
  const float* arv[2] = {(const float*)d_in[9], (const float*)d_in[15]};
  const float* ww_w[2] = {(const float*)d_in[16], (const float*)d_in[18]};
  const float* ww_b[2] = {(const float*)d_in[17], (const float*)d_in[19]};
  const float* lin_w = (const float*)d_in[20];
  const float* lin_b = (const float*)d_in[21];

  char* wp = (char*)d_ws;
  auto alloc = [&](size_t bytes) -> char* {
    char* p = wp;
    wp += (bytes + 255) & ~(size_t)255;
    return p;
  };
  float* XA = (float*)alloc((size_t)NT * CD * 4);
  float* XB = (float*)alloc((size_t)NT * CD * 4);
  float* OT = (float*)alloc((size_t)NT * CD * 4);
  float* P1 = (float*)alloc((size_t)NT * CD * 4);
  float* P2 = (float*)alloc((size_t)NT * CD * 4);
  __hip_bfloat16* FBF = (__hip_bfloat16*)alloc((size_t)NT * CD * 2);
  float* CT1 = (float*)alloc(128 * 128 * 4);
  float* CT2 = (float*)alloc(128 * 128 * 4);
  float* OFF1 = (float*)alloc(128 * 128 * 4);
  float* OFF2 = (float*)alloc(128 * 128 * 4);
  float* AL = (float*)alloc(NT * 4);
  float* AR_ = (float*)alloc(NT * 4);
  float* ARS = (float*)alloc(NT * 4);
  float* Q1L = (float*)alloc(NT * 4);
  float* Q2L = (float*)alloc(NT * 4);
  float* QCT1 = (float*)alloc(128 * 4);
  float* QCT2 = (float*)alloc(128 * 4);
  float* QOF1 = (float*)alloc(128 * 4);
  float* QOF2 = (float*)alloc(128 * 4);
  float* VP = (float*)alloc(2 * 258 * 4);
  float* WT1 = (float*)alloc(256 * 128 * 4);
  float* WT2 = (float*)alloc(256 * 128 * 4);
  float* WTL = (float*)alloc(128 * 128 * 4);
  int* RANK = (int*)alloc(NT * 4);
  int* PERM = (int*)alloc(NT * 4);
  int* DEG = (int*)alloc(2 * NN * 4);
  int* OFFS = (int*)alloc(2 * (NN + 1) * 4);
  int* CURS = (int*)alloc(2 * NN * 4);
  int* ADJ = (int*)alloc(2 * NE * 4);
  int* TK = (int*)alloc(8 * 4);

  // 1: prep (concat + transposes + params + DEG/TK zero)
  k_prep<<<512, 256, 0, stream>>>(x1, x2, XA, ww_w[0], ww_w[1], lin_w, WT1, WT2, WTL,
                                  wl_w[0], wl_b[0], wr_w[0], wr_b[0], alv[0], arv[0],
                                  wl_w[1], wl_b[1], wr_w[1], wr_b[1], alv[1], arv[1],
                                  VP, DEG, TK);
  // 2: deg || alar0 (+RANK zero)
  k_stage2<<<2560, 256, 0, stream>>>(ei1, ei2, DEG, XA, VP, AL, AR_, RANK);
  // 3: scanoff || rank0+perm0
  k_stage3<<<258, 256, 0, stream>>>(DEG, OFFS, CURS, AR_, RANK, PERM, ARS, TK);
  // 4: fill || scanA0+scanB0
  k_stage4<<<640, 256, 0, stream>>>(ei1, ei2, CURS, ADJ, XA, PERM, ARS,
                                    P1, P2, CT1, CT2, Q1L, Q2L, QCT1, QCT2,
                                    OFF1, OFF2, QOF1, QOF2, TK);
  // 5: combine0
  k_combine<<<4096, 256, 0, stream>>>(XA, AL, ARS, P1, P2, OFF1, OFF2, Q1L, Q2L,
                                      QOF1, QOF2, OT);
  // 6: aggr+gemm0 (+alar1, RANK zero)
  k_aggrgemm<<<1024, 256, 0, stream>>>(XA, OT, OFFS, ADJ, WT1, ww_b[0], XB,
                                       0, VP + 258, AL, AR_, RANK, WTL, lin_b, FBF);
  // 7: rank1+perm1
  k_rankperm1<<<256, 256, 0, stream>>>(AR_, RANK, PERM, ARS, TK);
  // 8: scanA1+scanB1
  k_scanA1<<<128, 256, 0, stream>>>(XB, PERM, ARS, P1, P2, CT1, CT2, Q1L, Q2L,
                                    QCT1, QCT2, OFF1, OFF2, QOF1, QOF2, TK);
  // 9: combine1
  k_combine<<<4096, 256, 0, stream>>>(XB, AL, ARS, P1, P2, OFF1, OFF2, Q1L, Q2L,
                                      QOF1, QOF2, OT);
  // 10: aggr+gemm1 (+lin -> FBF)
  k_aggrgemm<<<1024, 256, 0, stream>>>(XB, OT, OFFS, ADJ, WT2, ww_b[1], XA,
                                       1, VP, AL, AR_, RANK, WTL, lin_b, FBF);
  // 11: final
  k_final<<<dim3(64, 64), 256, 0, stream>>>((const unsigned short*)FBF, (float*)d_out);
}

// Round 10
// 319.557 us; speedup vs baseline: 4.3680x; 1.4104x over previous
//
#include <hip/hip_runtime.h>
#include <hip/hip_bf16.h>

#define NT 8192   // total nodes (2 graphs)
#define NN 4096   // nodes per graph
#define CD 128    // channels
#define NE 65536  // edges per graph

typedef __attribute__((ext_vector_type(8))) short bf16x8;
typedef __attribute__((ext_vector_type(16))) float f32x16;
typedef __attribute__((ext_vector_type(4))) float f32x4;

// ---------------- prep: weight transposes + attention params + DEG zero ----------------
__global__ __launch_bounds__(256) void k_prep(
    const float* __restrict__ W1, const float* __restrict__ W2, const float* __restrict__ WL,
    float* __restrict__ WT1, float* __restrict__ WT2, float* __restrict__ WTL,
    const float* __restrict__ wlw0, const float* __restrict__ wlb0,
    const float* __restrict__ wrw0, const float* __restrict__ wrb0,
    const float* __restrict__ al0, const float* __restrict__ ar0,
    const float* __restrict__ wlw1, const float* __restrict__ wlb1,
    const float* __restrict__ wrw1, const float* __restrict__ wrb1,
    const float* __restrict__ al1, const float* __restrict__ ar1,
    float* __restrict__ VP, int* __restrict__ DEG) {
  int b = blockIdx.x, tid = threadIdx.x;
  if (b < 320) {
    int idx = b * 256 + tid;
    if (idx < 32768) { int c = idx >> 8, k = idx & 255; WT1[k * 128 + c] = W1[idx]; }
    else if (idx < 65536) { int j = idx - 32768; int c = j >> 8, k = j & 255; WT2[k * 128 + c] = W2[j]; }
    else { int j = idx - 65536; int c = j >> 7, k = j & 127; WTL[k * 128 + c] = WL[j]; }
  } else if (b < 322) {
    int L = b - 320;
    const float* wlw = L ? wlw1 : wlw0;
    const float* wlb = L ? wlb1 : wlb0;
    const float* wrw = L ? wrw1 : wrw0;
    const float* wrb = L ? wrb1 : wrb0;
    const float* alv = L ? al1 : al0;
    const float* arv = L ? ar1 : ar0;
    float* vp = VP + L * 258;
    if (tid < 128) {
      int c = tid;
      float sl = 0.f, sr = 0.f;
      for (int h = 0; h < 128; ++h) {
        sl += wlw[h * 128 + c] * alv[h];
        sr += wrw[h * 128 + c] * arv[h];
      }
      vp[c] = sl;
      vp[128 + c] = sr;
      if (c < 2) {
        const float* bb = c ? wrb : wlb;
        const float* aa = c ? arv : alv;
        float s = 0.f;
        for (int h = 0; h < 128; ++h) s += bb[h] * aa[h];
        vp[256 + c] = s;
      }
    }
  } else {
    int idx = (b - 322) * 256 + tid;  // 8192
    DEG[idx] = 0;
  }
}

// ---------------- CSR build (once; edges shared by both layers) ----------------
__global__ void k_deg(const int* __restrict__ EI1, const int* __restrict__ EI2,
                      int* __restrict__ DEG) {
  int idx = blockIdx.x * 256 + threadIdx.x;   // 131072
  int g = idx >> 16, e = idx & 65535;
  const int* src = g ? EI2 : EI1;
  atomicAdd(&DEG[g * NN + src[e]], 1);
}

__global__ void k_scanoff(const int* __restrict__ DEG, int* __restrict__ OFFS,
                          int* __restrict__ CURS) {
  int g = blockIdx.x, tid = threadIdx.x;
  __shared__ int part[256];
  int loc[16];
  int s = 0;
  #pragma unroll
  for (int i = 0; i < 16; ++i) { loc[i] = s; s += DEG[g * NN + tid * 16 + i]; }
  part[tid] = s;
  __syncthreads();
  for (int d = 1; d < 256; d <<= 1) {
    int v = part[tid];
    int o = (tid >= d) ? part[tid - d] : 0;
    __syncthreads();
    part[tid] = v + o;
    __syncthreads();
  }
  int excl = tid ? part[tid - 1] : 0;
  #pragma unroll
  for (int i = 0; i < 16; ++i) {
    int o = excl + loc[i];
    OFFS[g * (NN + 1) + tid * 16 + i] = o;
    CURS[g * NN + tid * 16 + i] = o;
  }
  if (tid == 255) OFFS[g * (NN + 1) + NN] = part[255];
}

__global__ void k_fill(const int* __restrict__ EI1, const int* __restrict__ EI2,
                       int* __restrict__ CURS, int* __restrict__ ADJ) {
  int idx = blockIdx.x * 256 + threadIdx.x;
  int g = idx >> 16, e = idx & 65535;
  const int* ei = g ? EI2 : EI1;
  int s = ei[e], d = ei[NE + e];
  int pos = atomicAdd(&CURS[g * NN + s], 1);
  ADJ[g * NE + pos] = d;
}

// a_l[i] = X[i].vl + cl ; a_r[i] = X[i].vr + cr  (one wave per row); blocks 0..31 zero RANK
__global__ void k_alar(const float* __restrict__ X, const float* __restrict__ VP,
                       float* __restrict__ AL, float* __restrict__ AR,
                       int* __restrict__ RANK) {
  if (blockIdx.x < 32) RANK[blockIdx.x * 256 + threadIdx.x] = 0;
  int lane = threadIdx.x & 63;
  int row = blockIdx.x * 4 + (threadIdx.x >> 6);
  float x0 = X[row * 128 + lane], x1 = X[row * 128 + 64 + lane];
  float sl = x0 * VP[lane] + x1 * VP[64 + lane];
  float sr = x0 * VP[128 + lane] + x1 * VP[192 + lane];
  #pragma unroll
  for (int m = 1; m < 64; m <<= 1) {
    sl += __shfl_xor(sl, m, 64);
    sr += __shfl_xor(sr, m, 64);
  }
  if (lane == 0) { AL[row] = sl + VP[256]; AR[row] = sr + VP[257]; }
}

// rank of each j under total order (a_r, j)  -> O(N^2) chunked count, int atomics
__global__ void k_rank(const float* __restrict__ AR, int* __restrict__ RANK) {
  __shared__ float tile[1024];
  int j = blockIdx.x * 256 + threadIdx.x;
  int base = blockIdx.y * 1024;
  for (int t = threadIdx.x; t < 1024; t += 256) tile[t] = AR[base + t];
  __syncthreads();
  float aj = AR[j];
  int cnt = 0;
  #pragma unroll 8
  for (int u = 0; u < 1024; ++u) {
    float a2 = tile[u];
    cnt += (a2 < aj || (a2 == aj && (base + u) < j)) ? 1 : 0;
  }
  atomicAdd(&RANK[j], cnt);
}

// scatter permutation + sorted a_r
__global__ void k_perm(const int* __restrict__ RANK, const float* __restrict__ AR,
                       int* __restrict__ PERM, float* __restrict__ ARS) {
  int j = blockIdx.x * 256 + threadIdx.x;
  int r = RANK[j];
  PERM[r] = j;
  ARS[r] = AR[j];
}

// hierarchical prefix sums, 4-way t-split: 512 blocks = 128 chunks x 4 channel-quarters
// threads 256 = {array a} x {t-group g} x {32 channels}; serial chain 64 -> 16
__global__ __launch_bounds__(256) void k_scanA(
    const float* __restrict__ X, const int* __restrict__ PERM,
    const float* __restrict__ ARS,
    float* __restrict__ P1, float* __restrict__ P2,
    float* __restrict__ CT1, float* __restrict__ CT2,
    float* __restrict__ Q1L, float* __restrict__ Q2L,
    float* __restrict__ QCT1, float* __restrict__ QCT2) {
  __shared__ int pc[64];
  __shared__ float w[2][64];
  __shared__ float part[2][4][32];
  __shared__ float qpart[2][4];
  int b = blockIdx.x;
  int chunk = b >> 2, sub = b & 3;
  int tid = threadIdx.x;
  int a = tid >> 7;          // 0: exp(ar) path, 1: exp(0.2 ar) path
  int g = (tid >> 5) & 3;    // t-group (16 rows each)
  int cl = tid & 31;
  int c = sub * 32 + cl;
  if (tid < 64) {
    int r = chunk * 64 + tid;
    pc[tid] = PERM[r];
    float ar = ARS[r];
    w[0][tid] = __expf(ar);
    w[1][tid] = __expf(0.2f * ar);
  }
  __syncthreads();
  int t0 = g * 16;
  float loc[16];
  float acc = 0.f;
  #pragma unroll 4
  for (int t = 0; t < 16; ++t) {
    acc += w[a][t0 + t] * X[pc[t0 + t] * 128 + c];
    loc[t] = acc;
  }
  part[a][g][cl] = acc;
  float qloc[16];
  float qacc = 0.f;
  bool doQ = (sub == 0 && cl == 0);
  if (doQ) {
    for (int t = 0; t < 16; ++t) { qacc += w[a][t0 + t]; qloc[t] = qacc; }
    qpart[a][g] = qacc;
  }
  __syncthreads();
  float off = (g > 0 ? part[a][0][cl] : 0.f) + (g > 1 ? part[a][1][cl] : 0.f) +
              (g > 2 ? part[a][2][cl] : 0.f);
  float* P = a ? P2 : P1;
  #pragma unroll 4
  for (int t = 0; t < 16; ++t) P[(chunk * 64 + t0 + t) * 128 + c] = loc[t] + off;
  if (g == 3) (a ? CT2 : CT1)[chunk * 128 + c] = off + acc;
  if (doQ) {
    float qoff = (g > 0 ? qpart[a][0] : 0.f) + (g > 1 ? qpart[a][1] : 0.f) +
                 (g > 2 ? qpart[a][2] : 0.f);
    float* Q = a ? Q2L : Q1L;
    for (int t = 0; t < 16; ++t) Q[chunk * 64 + t0 + t] = qloc[t] + qoff;
    if (g == 3) (a ? QCT2 : QCT1)[chunk] = qoff + qacc;
  }
}

__global__ __launch_bounds__(320) void k_scanB(
    const float* __restrict__ CT1, const float* __restrict__ CT2,
    const float* __restrict__ QCT1, const float* __restrict__ QCT2,
    float* __restrict__ OFF1, float* __restrict__ OFF2,
    float* __restrict__ QOF1, float* __restrict__ QOF2) {
  int tid = threadIdx.x;
  if (tid < 128) {
    float acc = 0.f;
    #pragma unroll 8
    for (int ch = 0; ch < 128; ++ch) { acc += CT1[ch * 128 + tid]; OFF1[ch * 128 + tid] = acc; }
  } else if (tid < 256) {
    int c = tid - 128;
    float acc = 0.f;
    #pragma unroll 8
    for (int ch = 0; ch < 128; ++ch) { acc += CT2[ch * 128 + c]; OFF2[ch * 128 + c] = acc; }
  } else if (tid == 256) {
    float acc = 0.f;
    for (int ch = 0; ch < 128; ++ch) { acc += QCT1[ch]; QOF1[ch] = acc; }
  } else if (tid == 257) {
    float acc = 0.f;
    for (int ch = 0; ch < 128; ++ch) { acc += QCT2[ch]; QOF2[ch] = acc; }
  }
}

// ot[i] = x[i] - (A1*suffix1 + A2*prefix2)/(A1*qsuf1 + A2*qpre2)
__global__ void k_combine(const float* __restrict__ X, const float* __restrict__ AL,
                          const float* __restrict__ ARS,
                          const float* __restrict__ P1, const float* __restrict__ P2,
                          const float* __restrict__ OFF1, const float* __restrict__ OFF2,
                          const float* __restrict__ Q1L, const float* __restrict__ Q2L,
                          const float* __restrict__ QOF1, const float* __restrict__ QOF2,
                          float* __restrict__ OT) {
  int row = blockIdx.x * 2 + (threadIdx.x >> 7);
  int c = threadIdx.x & 127;
  float ali = AL[row];
  float A1 = __expf(ali), A2 = __expf(0.2f * ali);
  float xv = -ali;
  int lo = 0, hi = NT;
  while (lo < hi) {  // upper_bound: #{ar_j <= -al_i} (branch-2 count)
    int mid = (lo + hi) >> 1;
    if (ARS[mid] <= xv) lo = mid + 1; else hi = mid;
  }
  int b = lo - 1;
  float p1 = 0.f, p2 = 0.f, q1 = 0.f, q2 = 0.f;
  if (b >= 0) {
    int ch = b >> 6;
    p1 = P1[b * 128 + c] + (ch ? OFF1[(ch - 1) * 128 + c] : 0.f);
    p2 = P2[b * 128 + c] + (ch ? OFF2[(ch - 1) * 128 + c] : 0.f);
    q1 = Q1L[b] + (ch ? QOF1[ch - 1] : 0.f);
    q2 = Q2L[b] + (ch ? QOF2[ch - 1] : 0.f);
  }
  float T1 = OFF1[127 * 128 + c];
  float QT1 = QOF1[127];
  float num = A1 * (T1 - p1) + A2 * p2;
  float den = A1 * (QT1 - q1) + A2 * q2;
  OT[row * 128 + c] = X[row * 128 + c] - num / den;
}

// mean aggregation over CSR (self-loop included), feat = [x | ot]; wave-per-node, f32x4 lanes
__global__ __launch_bounds__(256) void k_aggr(const float* __restrict__ X,
                                              const float* __restrict__ OT,
                                              const int* __restrict__ OFFS,
                                              const int* __restrict__ ADJ,
                                              float* __restrict__ AGGR) {
  int node = blockIdx.x * 4 + (threadIdx.x >> 6);
  int lane = threadIdx.x & 63;
  int g = node >> 12, n = node & (NN - 1);
  const int* off = OFFS + g * (NN + 1);
  const int* adj = ADJ + g * NE;
  int beg = off[n], end = off[n + 1];
  const f32x4* src = (const f32x4*)((lane < 32 ? X : OT) + (size_t)g * NN * CD);
  int c4 = lane & 31;
  f32x4 acc = src[n * 32 + c4];
  for (int e = beg; e < end; ++e) {
    int d = adj[e];
    acc += src[d * 32 + c4];
  }
  f32x4 r = acc / (float)(end - beg + 1);
  ((f32x4*)AGGR)[(size_t)node * 64 + (lane < 32 ? c4 : 32 + c4)] = r;
}

// small GEMM: out[row][c] = sum_k act(A[row][k]) * WT[k][c] + bias[c]; 8 rows/block, LDS-staged A
template <int KD, bool RELU, bool OBF>
__global__ __launch_bounds__(128) void k_gemm(const float* __restrict__ A,
                                              const float* __restrict__ WT,
                                              const float* __restrict__ bias,
                                              void* __restrict__ out) {
  __shared__ float sA[8 * KD];
  int c = threadIdx.x;      // 128
  int r0 = blockIdx.x * 8;  // 8 rows per block
  for (int i = c; i < 8 * KD; i += 128) {
    float a = A[(size_t)r0 * KD + i];
    if (RELU) a = fmaxf(a, 0.f);
    sA[i] = a;
  }
  __syncthreads();
  float acc[8];
  float bc = bias[c];
  #pragma unroll
  for (int i = 0; i < 8; ++i) acc[i] = bc;
  for (int k = 0; k < KD; ++k) {
    float wv = WT[k * 128 + c];
    #pragma unroll
    for (int i = 0; i < 8; ++i) acc[i] += sA[i * KD + k] * wv;
  }
  if (OBF) {
    __hip_bfloat16* o = (__hip_bfloat16*)out;
    #pragma unroll
    for (int i = 0; i < 8; ++i) o[(r0 + i) * 128 + c] = __float2bfloat16(acc[i]);
  } else {
    float* o = (float*)out;
    #pragma unroll
    for (int i = 0; i < 8; ++i) o[(r0 + i) * 128 + c] = acc[i];
  }
}

// ---------------- final: out = sigmoid(F F^T), F bf16 8192x128 ----------------
__device__ inline f32x16 zero16() {
  f32x16 v;
  #pragma unroll
  for (int i = 0; i < 16; ++i) v[i] = 0.f;
  return v;
}

__device__ inline void store_frag(float* __restrict__ out, const f32x16& a,
                                  int grow0, int gcol) {
  #pragma unroll
  for (int r = 0; r < 16; ++r) {
    int rloc = (r & 3) + 8 * (r >> 2);  // C/D: row=(reg&3)+8*(reg>>2)+4*(lane>>5)
    float v = a[r];
    out[(size_t)(grow0 + rloc) * 8192 + gcol] =
        __builtin_amdgcn_rcpf(1.f + __expf(-v));
  }
}

__global__ __launch_bounds__(256) void k_final(const unsigned short* __restrict__ F,
                                               float* __restrict__ out) {
  __shared__ unsigned short AT[128 * 128];
  __shared__ unsigned short BT[128 * 128];
  int cb = blockIdx.x, rb = blockIdx.y;
  int tid = threadIdx.x;
  // stage two 128x128 bf16 tiles, XOR-swizzled rows (bank-conflict fix)
  #pragma unroll
  for (int q = 0; q < 8; ++q) {
    int idx = q * 256 + tid;       // 0..2047
    int r = idx >> 4, ck = idx & 15;
    unsigned off = (unsigned)((r * 256 + ck * 16) ^ ((r & 7) << 4));
    uint4 va = *(const uint4*)(F + (size_t)(rb * 128 + r) * 128 + ck * 8);
    *(uint4*)((char*)AT + off) = va;
    uint4 vb = *(const uint4*)(F + (size_t)(cb * 128 + r) * 128 + ck * 8);
    *(uint4*)((char*)BT + off) = vb;
  }
  __syncthreads();
  int lane = tid & 63, w = tid >> 6;
  int wr = w >> 1, wc = w & 1;
  int l31 = lane & 31, kh = lane >> 5;
  int xorm = (l31 & 7) << 4;
  int rowA0 = wr * 64 + l31, rowA1 = rowA0 + 32;
  int rowB0 = wc * 64 + l31, rowB1 = rowB0 + 32;
  f32x16 a00 = zero16(), a01 = zero16(), a10 = zero16(), a11 = zero16();
  #pragma unroll
  for (int ks = 0; ks < 8; ++ks) {
    int kb = ks * 32 + kh * 16;
    bf16x8 av0 = *(const bf16x8*)((const char*)AT + ((rowA0 * 256 + kb) ^ xorm));
    bf16x8 av1 = *(const bf16x8*)((const char*)AT + ((rowA1 * 256 + kb) ^ xorm));
    bf16x8 bv0 = *(const bf16x8*)((const char*)BT + ((rowB0 * 256 + kb) ^ xorm));
    bf16x8 bv1 = *(const bf16x8*)((const char*)BT + ((rowB1 * 256 + kb) ^ xorm));
    a00 = __builtin_amdgcn_mfma_f32_32x32x16_bf16(av0, bv0, a00, 0, 0, 0);
    a01 = __builtin_amdgcn_mfma_f32_32x32x16_bf16(av0, bv1, a01, 0, 0, 0);
    a10 = __builtin_amdgcn_mfma_f32_32x32x16_bf16(av1, bv0, a10, 0, 0, 0);
    a11 = __builtin_amdgcn_mfma_f32_32x32x16_bf16(av1, bv1, a11, 0, 0, 0);
  }
  int grow = rb * 128 + wr * 64 + 4 * kh;
  int gcol = cb * 128 + wc * 64 + l31;
  store_frag(out, a00, grow, gcol);
  store_frag(out, a01, grow, gcol + 32);
  store_frag(out, a10, grow + 32, gcol);
  store_frag(out, a11, grow + 32, gcol + 32);
}

// ---------------- host ----------------
extern "C" void kernel_launch(void* const* d_in, const int* in_sizes, int n_in,
                              void* d_out, int out_size, void* d_ws, size_t ws_size,
                              hipStream_t stream) {
  (void)in_sizes; (void)n_in; (void)out_size; (void)ws_size;
  const float* x1 = (const float*)d_in[0];
  const float* x2 = (const float*)d_in[1];
  const int* ei1 = (const int*)d_in[2];
  const int* ei2 = (const int*)d_in[3];
  const float* wl_w[2] = {(const float*)d_in[4], (const float*)d_in[10]};
  const float* wl_b[2] = {(const float*)d_in[5], (const float*)d_in[11]};
  const float* wr_w[2] = {(const float*)d_in[6], (const float*)d_in[12]};
  const float* wr_b[2] = {(const float*)d_in[7], (const float*)d_in[13]};
  const float* alv[2] = {(const float*)d_in[8], (const float*)d_in[14]};
  const float* arv[2] = {(const float*)d_in[9], (const float*)d_in[15]};
  const float* ww_w[2] = {(const float*)d_in[16], (const float*)d_in[18]};
  const float* ww_b[2] = {(const float*)d_in[17], (const float*)d_in[19]};
  const float* lin_w = (const float*)d_in[20];
  const float* lin_b = (const float*)d_in[21];

  char* wp = (char*)d_ws;
  auto alloc = [&](size_t b) -> char* {
    char* p = wp;
    wp += (b + 255) & ~(size_t)255;
    return p;
  };
  float* XA = (float*)alloc((size_t)NT * CD * 4);
  float* XB = (float*)alloc((size_t)NT * CD * 4);
  float* OT = (float*)alloc((size_t)NT * CD * 4);
  float* P1 = (float*)alloc((size_t)NT * CD * 4);
  float* P2 = (float*)alloc((size_t)NT * CD * 4);
  float* AGGR = P1;  // P1,P2 dead once k_combine ran; k_aggr reuses the 8MB
  float* CT1 = (float*)alloc(128 * 128 * 4);
  float* CT2 = (float*)alloc(128 * 128 * 4);
  float* OFF1 = (float*)alloc(128 * 128 * 4);
  float* OFF2 = (float*)alloc(128 * 128 * 4);
  float* AL = (float*)alloc(NT * 4);
  float* AR_ = (float*)alloc(NT * 4);
  float* ARS = (float*)alloc(NT * 4);
  float* Q1L = (float*)alloc(NT * 4);
  float* Q2L = (float*)alloc(NT * 4);
  float* QCT1 = (float*)alloc(128 * 4);
  float* QCT2 = (float*)alloc(128 * 4);
  float* QOF1 = (float*)alloc(128 * 4);
  float* QOF2 = (float*)alloc(128 * 4);
  float* VP = (float*)alloc(2 * 258 * 4);
  float* WT1 = (float*)alloc(256 * 128 * 4);
  float* WT2 = (float*)alloc(256 * 128 * 4);
  float* WTL = (float*)alloc(128 * 128 * 4);
  int* RANK = (int*)alloc(NT * 4);
  int* PERM = (int*)alloc(NT * 4);
  int* DEG = (int*)alloc(2 * NN * 4);
  int* OFFS = (int*)alloc(2 * (NN + 1) * 4);
  int* CURS = (int*)alloc(2 * NN * 4);
  int* ADJ = (int*)alloc(2 * NE * 4);
  __hip_bfloat16* FBF = (__hip_bfloat16*)OT;  // OT dead after last k_aggr

  // X = concat(x1, x2)
  hipMemcpyAsync(XA, x1, (size_t)NN * CD * 4, hipMemcpyDeviceToDevice, stream);
  hipMemcpyAsync(XA + (size_t)NN * CD, x2, (size_t)NN * CD * 4, hipMemcpyDeviceToDevice, stream);
  k_prep<<<354, 256, 0, stream>>>(ww_w[0], ww_w[1], lin_w, WT1, WT2, WTL,
                                  wl_w[0], wl_b[0], wr_w[0], wr_b[0], alv[0], arv[0],
                                  wl_w[1], wl_b[1], wr_w[1], wr_b[1], alv[1], arv[1],
                                  VP, DEG);
  k_deg<<<512, 256, 0, stream>>>(ei1, ei2, DEG);
  k_scanoff<<<2, 256, 0, stream>>>(DEG, OFFS, CURS);
  k_fill<<<512, 256, 0, stream>>>(ei1, ei2, CURS, ADJ);

  float* X = XA;
  float* XN = XB;
  for (int L = 0; L < 2; ++L) {
    k_alar<<<2048, 256, 0, stream>>>(X, VP + L * 258, AL, AR_, RANK);
    k_rank<<<dim3(32, 8), 256, 0, stream>>>(AR_, RANK);
    k_perm<<<32, 256, 0, stream>>>(RANK, AR_, PERM, ARS);
    k_scanA<<<512, 256, 0, stream>>>(X, PERM, ARS, P1, P2, CT1, CT2, Q1L, Q2L, QCT1, QCT2);
    k_scanB<<<1, 320, 0, stream>>>(CT1, CT2, QCT1, QCT2, OFF1, OFF2, QOF1, QOF2);
    k_combine<<<4096, 256, 0, stream>>>(X, AL, ARS, P1, P2, OFF1, OFF2, Q1L, Q2L, QOF1, QOF2, OT);
    k_aggr<<<2048, 256, 0, stream>>>(X, OT, OFFS, ADJ, AGGR);
    k_gemm<256, true, false><<<1024, 128, 0, stream>>>(AGGR, L ? WT2 : WT1, ww_b[L], XN);
    float* t = X; X = XN; XN = t;
  }
  // feats (bf16) = X @ lin^T + lin_b
  k_gemm<128, false, true><<<1024, 128, 0, stream>>>(X, WTL, lin_b, FBF);
  // out = sigmoid(F F^T)
  k_final<<<dim3(64, 64), 256, 0, stream>>>((const unsigned short*)FBF, (float*)d_out);
}

// Round 11
// 301.234 us; speedup vs baseline: 4.6337x; 1.0608x over previous
//
#include <hip/hip_runtime.h>
#include <hip/hip_bf16.h>

#define NT 8192   // total nodes (2 graphs)
#define NN 4096   // nodes per graph
#define CD 128    // channels
#define NE 65536  // edges per graph

typedef __attribute__((ext_vector_type(8))) short bf16x8;
typedef __attribute__((ext_vector_type(16))) float f32x16;
typedef __attribute__((ext_vector_type(4))) float f32x4;

// ---------------- prep: concat + weight transposes + attention params + DEG zero ----------------
__global__ __launch_bounds__(256) void k_prep(
    const float* __restrict__ x1, const float* __restrict__ x2, float* __restrict__ X,
    const float* __restrict__ W1, const float* __restrict__ W2, const float* __restrict__ WL,
    float* __restrict__ WT1, float* __restrict__ WT2, float* __restrict__ WTL,
    const float* __restrict__ wlw0, const float* __restrict__ wlb0,
    const float* __restrict__ wrw0, const float* __restrict__ wrb0,
    const float* __restrict__ al0, const float* __restrict__ ar0,
    const float* __restrict__ wlw1, const float* __restrict__ wlb1,
    const float* __restrict__ wrw1, const float* __restrict__ wrb1,
    const float* __restrict__ al1, const float* __restrict__ ar1,
    float* __restrict__ VP, int* __restrict__ DEG) {
  int b = blockIdx.x, tid = threadIdx.x;
  int gid = b * 256 + tid;  // 0..131071
  {
    const f32x4* s1 = (const f32x4*)x1;
    const f32x4* s2 = (const f32x4*)x2;
    f32x4* d = (f32x4*)X;
    d[gid] = s1[gid];
    d[gid + NN * CD / 4] = s2[gid];
  }
  if (gid < 81920) {
    int idx = gid;
    if (idx < 32768) { int c = idx >> 8, k = idx & 255; WT1[k * 128 + c] = W1[idx]; }
    else if (idx < 65536) { int j = idx - 32768; int c = j >> 8, k = j & 255; WT2[k * 128 + c] = W2[j]; }
    else { int j = idx - 65536; int c = j >> 7, k = j & 127; WTL[k * 128 + c] = WL[j]; }
  }
  if ((b == 508 || b == 509) && tid < 128) {
    int L = b - 508;
    const float* wlw = L ? wlw1 : wlw0;
    const float* wlb = L ? wlb1 : wlb0;
    const float* wrw = L ? wrw1 : wrw0;
    const float* wrb = L ? wrb1 : wrb0;
    const float* alv = L ? al1 : al0;
    const float* arv = L ? ar1 : ar0;
    float* vp = VP + L * 258;
    int c = tid;
    float sl = 0.f, sr = 0.f;
    for (int h = 0; h < 128; ++h) {
      sl += wlw[h * 128 + c] * alv[h];
      sr += wrw[h * 128 + c] * arv[h];
    }
    vp[c] = sl;
    vp[128 + c] = sr;
    if (c < 2) {
      const float* bb = c ? wrb : wlb;
      const float* aa = c ? arv : alv;
      float s = 0.f;
      for (int h = 0; h < 128; ++h) s += bb[h] * aa[h];
      vp[256 + c] = s;
    }
  }
  if (gid < 2 * NN) DEG[gid] = 0;
}

// ---------------- shared bodies ----------------
__device__ inline void alar_row(const float* __restrict__ X, const float* __restrict__ VP,
                                float* __restrict__ AL, float* __restrict__ AR,
                                int row, int lane) {
  float x0 = X[row * 128 + lane], x1 = X[row * 128 + 64 + lane];
  float sl = x0 * VP[lane] + x1 * VP[64 + lane];
  float sr = x0 * VP[128 + lane] + x1 * VP[192 + lane];
  #pragma unroll
  for (int m = 1; m < 64; m <<= 1) {
    sl += __shfl_xor(sl, m, 64);
    sr += __shfl_xor(sr, m, 64);
  }
  if (lane == 0) { AL[row] = sl + VP[256]; AR[row] = sr + VP[257]; }
}

__device__ void rank_body(int rb, int tid, const float* __restrict__ AR,
                          int* __restrict__ RANK) {
  __shared__ float tile[1024];
  int jb = rb & 31, tb = rb >> 5;
  int base = tb * 1024;
  for (int t = tid; t < 1024; t += 256) tile[t] = AR[base + t];
  __syncthreads();
  int j = jb * 256 + tid;
  float aj = AR[j];
  int cnt = 0;
  #pragma unroll 8
  for (int u = 0; u < 1024; ++u) {
    float a2 = tile[u];
    cnt += (a2 < aj || (a2 == aj && (base + u) < j)) ? 1 : 0;
  }
  atomicAdd(&RANK[j], cnt);
}

__device__ void scanoff_body(int g, int tid, const int* __restrict__ DEG,
                             int* __restrict__ OFFS, int* __restrict__ CURS) {
  __shared__ int part[256];
  int loc[16];
  int s = 0;
  #pragma unroll
  for (int i = 0; i < 16; ++i) { loc[i] = s; s += DEG[g * NN + tid * 16 + i]; }
  part[tid] = s;
  __syncthreads();
  for (int d = 1; d < 256; d <<= 1) {
    int v = part[tid];
    int o = (tid >= d) ? part[tid - d] : 0;
    __syncthreads();
    part[tid] = v + o;
    __syncthreads();
  }
  int excl = tid ? part[tid - 1] : 0;
  #pragma unroll
  for (int i = 0; i < 16; ++i) {
    int o = excl + loc[i];
    OFFS[g * (NN + 1) + tid * 16 + i] = o;
    CURS[g * NN + tid * 16 + i] = o;
  }
  if (tid == 255) OFFS[g * (NN + 1) + NN] = part[255];
}

// ---------------- s2: deg atomics || alar0 (+RANK zero) ----------------
__global__ __launch_bounds__(256) void k_s2(
    const int* __restrict__ EI1, const int* __restrict__ EI2, int* __restrict__ DEG,
    const float* __restrict__ X, const float* __restrict__ VP0,
    float* __restrict__ AL, float* __restrict__ AR, int* __restrict__ RANK) {
  int b = blockIdx.x, tid = threadIdx.x;
  if (b < 512) {
    int gid = b * 256 + tid;
    int g = gid >> 16, e = gid & 65535;
    const int* src = g ? EI2 : EI1;
    atomicAdd(&DEG[g * NN + src[e]], 1);
  } else {
    int bb = b - 512;
    if (bb < 32) RANK[bb * 256 + tid] = 0;
    alar_row(X, VP0, AL, AR, bb * 4 + (tid >> 6), tid & 63);
  }
}

// ---------------- s3: scanoff || rank0 ----------------
__global__ __launch_bounds__(256) void k_s3(
    const int* __restrict__ DEG, int* __restrict__ OFFS, int* __restrict__ CURS,
    const float* __restrict__ AR, int* __restrict__ RANK) {
  int b = blockIdx.x, tid = threadIdx.x;
  if (b < 2) scanoff_body(b, tid, DEG, OFFS, CURS);
  else rank_body(b - 2, tid, AR, RANK);
}

// ---------------- s4: fill || perm0 ----------------
__global__ __launch_bounds__(256) void k_s4(
    const int* __restrict__ EI1, const int* __restrict__ EI2,
    int* __restrict__ CURS, int* __restrict__ ADJ,
    const int* __restrict__ RANK, const float* __restrict__ AR,
    int* __restrict__ PERM, float* __restrict__ ARS) {
  int b = blockIdx.x, tid = threadIdx.x;
  if (b < 512) {
    int gid = b * 256 + tid;
    int g = gid >> 16, e = gid & 65535;
    const int* ei = g ? EI2 : EI1;
    int s = ei[e], d = ei[NE + e];
    int pos = atomicAdd(&CURS[g * NN + s], 1);
    ADJ[g * NE + pos] = d;
  } else {
    int j = (b - 512) * 256 + tid;
    int r = RANK[j];
    PERM[r] = j;
    ARS[r] = AR[j];
  }
}

// plain rank (layer 1) and perm (layer 1)
__global__ void k_rank(const float* __restrict__ AR, int* __restrict__ RANK) {
  rank_body(blockIdx.x, threadIdx.x, AR, RANK);
}
__global__ void k_perm(const int* __restrict__ RANK, const float* __restrict__ AR,
                       int* __restrict__ PERM, float* __restrict__ ARS) {
  int j = blockIdx.x * 256 + threadIdx.x;
  int r = RANK[j];
  PERM[r] = j;
  ARS[r] = AR[j];
}

// hierarchical prefix sums, 4-way t-split (512 blocks); blocks<32 zero RANK for next rank pass
__global__ __launch_bounds__(256) void k_scanA(
    const float* __restrict__ X, const int* __restrict__ PERM,
    const float* __restrict__ ARS, int* __restrict__ RANK,
    float* __restrict__ P1, float* __restrict__ P2,
    float* __restrict__ CT1, float* __restrict__ CT2,
    float* __restrict__ Q1L, float* __restrict__ Q2L,
    float* __restrict__ QCT1, float* __restrict__ QCT2) {
  __shared__ int pc[64];
  __shared__ float w[2][64];
  __shared__ float part[2][4][32];
  __shared__ float qpart[2][4];
  int b = blockIdx.x;
  if (b < 32) RANK[b * 256 + threadIdx.x] = 0;
  int chunk = b >> 2, sub = b & 3;
  int tid = threadIdx.x;
  int a = tid >> 7;
  int g = (tid >> 5) & 3;
  int cl = tid & 31;
  int c = sub * 32 + cl;
  if (tid < 64) {
    int r = chunk * 64 + tid;
    pc[tid] = PERM[r];
    float ar = ARS[r];
    w[0][tid] = __expf(ar);
    w[1][tid] = __expf(0.2f * ar);
  }
  __syncthreads();
  int t0 = g * 16;
  float loc[16];
  float acc = 0.f;
  #pragma unroll 4
  for (int t = 0; t < 16; ++t) {
    acc += w[a][t0 + t] * X[pc[t0 + t] * 128 + c];
    loc[t] = acc;
  }
  part[a][g][cl] = acc;
  float qloc[16];
  float qacc = 0.f;
  bool doQ = (sub == 0 && cl == 0);
  if (doQ) {
    for (int t = 0; t < 16; ++t) { qacc += w[a][t0 + t]; qloc[t] = qacc; }
    qpart[a][g] = qacc;
  }
  __syncthreads();
  float off = (g > 0 ? part[a][0][cl] : 0.f) + (g > 1 ? part[a][1][cl] : 0.f) +
              (g > 2 ? part[a][2][cl] : 0.f);
  float* P = a ? P2 : P1;
  #pragma unroll 4
  for (int t = 0; t < 16; ++t) P[(chunk * 64 + t0 + t) * 128 + c] = loc[t] + off;
  if (g == 3) (a ? CT2 : CT1)[chunk * 128 + c] = off + acc;
  if (doQ) {
    float qoff = (g > 0 ? qpart[a][0] : 0.f) + (g > 1 ? qpart[a][1] : 0.f) +
                 (g > 2 ? qpart[a][2] : 0.f);
    float* Q = a ? Q2L : Q1L;
    for (int t = 0; t < 16; ++t) Q[chunk * 64 + t0 + t] = qloc[t] + qoff;
    if (g == 3) (a ? QCT2 : QCT1)[chunk] = qoff + qacc;
  }
}

__global__ __launch_bounds__(320) void k_scanB(
    const float* __restrict__ CT1, const float* __restrict__ CT2,
    const float* __restrict__ QCT1, const float* __restrict__ QCT2,
    float* __restrict__ OFF1, float* __restrict__ OFF2,
    float* __restrict__ QOF1, float* __restrict__ QOF2) {
  int tid = threadIdx.x;
  if (tid < 128) {
    float acc = 0.f;
    #pragma unroll 8
    for (int ch = 0; ch < 128; ++ch) { acc += CT1[ch * 128 + tid]; OFF1[ch * 128 + tid] = acc; }
  } else if (tid < 256) {
    int c = tid - 128;
    float acc = 0.f;
    #pragma unroll 8
    for (int ch = 0; ch < 128; ++ch) { acc += CT2[ch * 128 + c]; OFF2[ch * 128 + c] = acc; }
  } else if (tid == 256) {
    float acc = 0.f;
    for (int ch = 0; ch < 128; ++ch) { acc += QCT1[ch]; QOF1[ch] = acc; }
  } else if (tid == 257) {
    float acc = 0.f;
    for (int ch = 0; ch < 128; ++ch) { acc += QCT2[ch]; QOF2[ch] = acc; }
  }
}

// ot[i] = x[i] - (A1*suffix1 + A2*prefix2)/(A1*qsuf1 + A2*qpre2)
__global__ void k_combine(const float* __restrict__ X, const float* __restrict__ AL,
                          const float* __restrict__ ARS,
                          const float* __restrict__ P1, const float* __restrict__ P2,
                          const float* __restrict__ OFF1, const float* __restrict__ OFF2,
                          const float* __restrict__ Q1L, const float* __restrict__ Q2L,
                          const float* __restrict__ QOF1, const float* __restrict__ QOF2,
                          float* __restrict__ OT) {
  int row = blockIdx.x * 2 + (threadIdx.x >> 7);
  int c = threadIdx.x & 127;
  float ali = AL[row];
  float A1 = __expf(ali), A2 = __expf(0.2f * ali);
  float xv = -ali;
  int lo = 0, hi = NT;
  while (lo < hi) {
    int mid = (lo + hi) >> 1;
    if (ARS[mid] <= xv) lo = mid + 1; else hi = mid;
  }
  int b = lo - 1;
  float p1 = 0.f, p2 = 0.f, q1 = 0.f, q2 = 0.f;
  if (b >= 0) {
    int ch = b >> 6;
    p1 = P1[b * 128 + c] + (ch ? OFF1[(ch - 1) * 128 + c] : 0.f);
    p2 = P2[b * 128 + c] + (ch ? OFF2[(ch - 1) * 128 + c] : 0.f);
    q1 = Q1L[b] + (ch ? QOF1[ch - 1] : 0.f);
    q2 = Q2L[b] + (ch ? QOF2[ch - 1] : 0.f);
  }
  float T1 = OFF1[127 * 128 + c];
  float QT1 = QOF1[127];
  float num = A1 * (T1 - p1) + A2 * p2;
  float den = A1 * (QT1 - q1) + A2 * q2;
  OT[row * 128 + c] = X[row * 128 + c] - num / den;
}

// mean aggregation over CSR (self-loop included); wave-per-node, f32x4 lanes
__global__ __launch_bounds__(256) void k_aggr(const float* __restrict__ X,
                                              const float* __restrict__ OT,
                                              const int* __restrict__ OFFS,
                                              const int* __restrict__ ADJ,
                                              float* __restrict__ AGGR) {
  int node = blockIdx.x * 4 + (threadIdx.x >> 6);
  int lane = threadIdx.x & 63;
  int g = node >> 12, n = node & (NN - 1);
  const int* off = OFFS + g * (NN + 1);
  const int* adj = ADJ + g * NE;
  int beg = off[n], end = off[n + 1];
  const f32x4* src = (const f32x4*)((lane < 32 ? X : OT) + (size_t)g * NN * CD);
  int c4 = lane & 31;
  f32x4 acc = src[n * 32 + c4];
  for (int e = beg; e < end; ++e) {
    int d = adj[e];
    acc += src[d * 32 + c4];
  }
  f32x4 r = acc / (float)(end - beg + 1);
  ((f32x4*)AGGR)[(size_t)node * 64 + (lane < 32 ? c4 : 32 + c4)] = r;
}

// gemm0 (relu(aggr)@WT+b -> XN) + alar(next layer) epilogue
__global__ __launch_bounds__(128) void k_gemmA(const float* __restrict__ A,
                                               const float* __restrict__ WT,
                                               const float* __restrict__ bias,
                                               float* __restrict__ XN,
                                               const float* __restrict__ VP1,
                                               float* __restrict__ AL,
                                               float* __restrict__ AR) {
  __shared__ float sA[8 * 256];
  __shared__ float sB[8 * 128];
  int c = threadIdx.x;
  int r0 = blockIdx.x * 8;
  for (int i = c; i < 8 * 256; i += 128) sA[i] = fmaxf(A[(size_t)r0 * 256 + i], 0.f);
  __syncthreads();
  float acc[8];
  float bc = bias[c];
  #pragma unroll
  for (int i = 0; i < 8; ++i) acc[i] = bc;
  for (int k = 0; k < 256; ++k) {
    float wv = WT[k * 128 + c];
    #pragma unroll
    for (int i = 0; i < 8; ++i) acc[i] += sA[i * 256 + k] * wv;
  }
  #pragma unroll
  for (int i = 0; i < 8; ++i) {
    XN[(r0 + i) * 128 + c] = acc[i];
    sB[i * 128 + c] = acc[i];
  }
  __syncthreads();
  int lane = threadIdx.x & 63, wv_ = threadIdx.x >> 6;  // 2 waves, 4 rows each
  #pragma unroll
  for (int i = 0; i < 4; ++i) {
    int row = wv_ * 4 + i;
    float x0 = sB[row * 128 + lane], x1 = sB[row * 128 + 64 + lane];
    float sl = x0 * VP1[lane] + x1 * VP1[64 + lane];
    float sr = x0 * VP1[128 + lane] + x1 * VP1[192 + lane];
    #pragma unroll
    for (int m = 1; m < 64; m <<= 1) {
      sl += __shfl_xor(sl, m, 64);
      sr += __shfl_xor(sr, m, 64);
    }
    if (lane == 0) { AL[r0 + row] = sl + VP1[256]; AR[r0 + row] = sr + VP1[257]; }
  }
}

// gemm1 (relu(aggr)@WT+b) + lin epilogue -> FBF bf16 (XN never hits global)
__global__ __launch_bounds__(128) void k_gemmB(const float* __restrict__ A,
                                               const float* __restrict__ WT,
                                               const float* __restrict__ bias,
                                               const float* __restrict__ WTL,
                                               const float* __restrict__ LINB,
                                               __hip_bfloat16* __restrict__ FBF) {
  __shared__ float sA[8 * 256];
  __shared__ float sB[8 * 128];
  int c = threadIdx.x;
  int r0 = blockIdx.x * 8;
  for (int i = c; i < 8 * 256; i += 128) sA[i] = fmaxf(A[(size_t)r0 * 256 + i], 0.f);
  __syncthreads();
  float acc[8];
  float bc = bias[c];
  #pragma unroll
  for (int i = 0; i < 8; ++i) acc[i] = bc;
  for (int k = 0; k < 256; ++k) {
    float wv = WT[k * 128 + c];
    #pragma unroll
    for (int i = 0; i < 8; ++i) acc[i] += sA[i * 256 + k] * wv;
  }
  #pragma unroll
  for (int i = 0; i < 8; ++i) sB[i * 128 + c] = acc[i];
  __syncthreads();
  float acl[8];
  float lb = LINB[c];
  #pragma unroll
  for (int i = 0; i < 8; ++i) acl[i] = lb;
  for (int k = 0; k < 128; ++k) {
    float wl = WTL[k * 128 + c];
    #pragma unroll
    for (int i = 0; i < 8; ++i) acl[i] += sB[i * 128 + k] * wl;
  }
  #pragma unroll
  for (int i = 0; i < 8; ++i) FBF[(r0 + i) * 128 + c] = __float2bfloat16(acl[i]);
}

// ---------------- final: out = sigmoid(F F^T), F bf16 8192x128 ----------------
__device__ inline f32x16 zero16() {
  f32x16 v;
  #pragma unroll
  for (int i = 0; i < 16; ++i) v[i] = 0.f;
  return v;
}

__device__ inline void store_frag(float* __restrict__ out, const f32x16& a,
                                  int grow0, int gcol) {
  #pragma unroll
  for (int r = 0; r < 16; ++r) {
    int rloc = (r & 3) + 8 * (r >> 2);  // C/D: row=(reg&3)+8*(reg>>2)+4*(lane>>5)
    float v = a[r];
    out[(size_t)(grow0 + rloc) * 8192 + gcol] =
        __builtin_amdgcn_rcpf(1.f + __expf(-v));
  }
}

__global__ __launch_bounds__(256) void k_final(const unsigned short* __restrict__ F,
                                               float* __restrict__ out) {
  __shared__ unsigned short AT[128 * 128];
  __shared__ unsigned short BT[128 * 128];
  int cb = blockIdx.x, rb = blockIdx.y;
  int tid = threadIdx.x;
  #pragma unroll
  for (int q = 0; q < 8; ++q) {
    int idx = q * 256 + tid;
    int r = idx >> 4, ck = idx & 15;
    unsigned off = (unsigned)((r * 256 + ck * 16) ^ ((r & 7) << 4));
    uint4 va = *(const uint4*)(F + (size_t)(rb * 128 + r) * 128 + ck * 8);
    *(uint4*)((char*)AT + off) = va;
    uint4 vb = *(const uint4*)(F + (size_t)(cb * 128 + r) * 128 + ck * 8);
    *(uint4*)((char*)BT + off) = vb;
  }
  __syncthreads();
  int lane = tid & 63, w = tid >> 6;
  int wr = w >> 1, wc = w & 1;
  int l31 = lane & 31, kh = lane >> 5;
  int xorm = (l31 & 7) << 4;
  int rowA0 = wr * 64 + l31, rowA1 = rowA0 + 32;
  int rowB0 = wc * 64 + l31, rowB1 = rowB0 + 32;
  f32x16 a00 = zero16(), a01 = zero16(), a10 = zero16(), a11 = zero16();
  #pragma unroll
  for (int ks = 0; ks < 8; ++ks) {
    int kb = ks * 32 + kh * 16;
    bf16x8 av0 = *(const bf16x8*)((const char*)AT + ((rowA0 * 256 + kb) ^ xorm));
    bf16x8 av1 = *(const bf16x8*)((const char*)AT + ((rowA1 * 256 + kb) ^ xorm));
    bf16x8 bv0 = *(const bf16x8*)((const char*)BT + ((rowB0 * 256 + kb) ^ xorm));
    bf16x8 bv1 = *(const bf16x8*)((const char*)BT + ((rowB1 * 256 + kb) ^ xorm));
    a00 = __builtin_amdgcn_mfma_f32_32x32x16_bf16(av0, bv0, a00, 0, 0, 0);
    a01 = __builtin_amdgcn_mfma_f32_32x32x16_bf16(av0, bv1, a01, 0, 0, 0);
    a10 = __builtin_amdgcn_mfma_f32_32x32x16_bf16(av1, bv0, a10, 0, 0, 0);
    a11 = __builtin_amdgcn_mfma_f32_32x32x16_bf16(av1, bv1, a11, 0, 0, 0);
  }
  int grow = rb * 128 + wr * 64 + 4 * kh;
  int gcol = cb * 128 + wc * 64 + l31;
  store_frag(out, a00, grow, gcol);
  store_frag(out, a01, grow, gcol + 32);
  store_frag(out, a10, grow + 32, gcol);
  store_frag(out, a11, grow + 32, gcol + 32);
}

// ---------------- host ----------------
extern "C" void kernel_launch(void* const* d_in, const int* in_sizes, int n_in,
                              void* d_out, int out_size, void* d_ws, size_t ws_size,
                              hipStream_t stream) {
  (void)in_sizes; (void)n_in; (void)out_size; (void)ws_size;
  const float* x1 = (const float*)d_in[0];
  const float* x2 = (const float*)d_in[1];
  const int* ei1 = (const int*)d_in[2];
  const int* ei2 = (const int*)d_in[3];
  const float* wl_w[2] = {(const float*)d_in[4], (const float*)d_in[10]};
  const float* wl_b[2] = {(const float*)d_in[5], (const float*)d_in[11]};
  const float* wr_w[2] = {(const float*)d_in[6], (const float*)d_in[12]};
  const float* wr_b[2] = {(const float*)d_in[7], (const float*)d_in[13]};
  const float* alv[2] = {(const float*)d_in[8], (const float*)d_in[14]};
  const float* arv[2] = {(const float*)d_in[9], (const float*)d_in[15]};
  const float* ww_w[2] = {(const float*)d_in[16], (const float*)d_in[18]};
  const float* ww_b[2] = {(const float*)d_in[17], (const float*)d_in[19]};
  const float* lin_w = (const float*)d_in[20];
  const float* lin_b = (const float*)d_in[21];

  char* wp = (char*)d_ws;
  auto alloc = [&](size_t b) -> char* {
    char* p = wp;
    wp += (b + 255) & ~(size_t)255;
    return p;
  };
  float* XA = (float*)alloc((size_t)NT * CD * 4);
  float* XB = (float*)alloc((size_t)NT * CD * 4);
  float* OT = (float*)alloc((size_t)NT * CD * 4);
  float* P1 = (float*)alloc((size_t)NT * CD * 4);
  float* P2 = (float*)alloc((size_t)NT * CD * 4);
  float* AGGR = P1;  // P1,P2 dead once k_combine ran; k_aggr reuses the 8MB
  float* CT1 = (float*)alloc(128 * 128 * 4);
  float* CT2 = (float*)alloc(128 * 128 * 4);
  float* OFF1 = (float*)alloc(128 * 128 * 4);
  float* OFF2 = (float*)alloc(128 * 128 * 4);
  float* AL = (float*)alloc(NT * 4);
  float* AR_ = (float*)alloc(NT * 4);
  float* ARS = (float*)alloc(NT * 4);
  float* Q1L = (float*)alloc(NT * 4);
  float* Q2L = (float*)alloc(NT * 4);
  float* QCT1 = (float*)alloc(128 * 4);
  float* QCT2 = (float*)alloc(128 * 4);
  float* QOF1 = (float*)alloc(128 * 4);
  float* QOF2 = (float*)alloc(128 * 4);
  float* VP = (float*)alloc(2 * 258 * 4);
  float* WT1 = (float*)alloc(256 * 128 * 4);
  float* WT2 = (float*)alloc(256 * 128 * 4);
  float* WTL = (float*)alloc(128 * 128 * 4);
  int* RANK = (int*)alloc(NT * 4);
  int* PERM = (int*)alloc(NT * 4);
  int* DEG = (int*)alloc(2 * NN * 4);
  int* OFFS = (int*)alloc(2 * (NN + 1) * 4);
  int* CURS = (int*)alloc(2 * NN * 4);
  int* ADJ = (int*)alloc(2 * NE * 4);
  __hip_bfloat16* FBF = (__hip_bfloat16*)OT;  // OT dead after aggr1 (gemmB reads AGGR only)

  // 1: prep (concat + transposes + params + DEG zero)
  k_prep<<<512, 256, 0, stream>>>(x1, x2, XA, ww_w[0], ww_w[1], lin_w, WT1, WT2, WTL,
                                  wl_w[0], wl_b[0], wr_w[0], wr_b[0], alv[0], arv[0],
                                  wl_w[1], wl_b[1], wr_w[1], wr_b[1], alv[1], arv[1],
                                  VP, DEG);
  // 2: deg || alar0 (+RANK zero)
  k_s2<<<2560, 256, 0, stream>>>(ei1, ei2, DEG, XA, VP, AL, AR_, RANK);
  // 3: scanoff || rank0
  k_s3<<<258, 256, 0, stream>>>(DEG, OFFS, CURS, AR_, RANK);
  // 4: fill || perm0
  k_s4<<<544, 256, 0, stream>>>(ei1, ei2, CURS, ADJ, RANK, AR_, PERM, ARS);
  // 5: scanA0 (+RANK zero for layer1)
  k_scanA<<<512, 256, 0, stream>>>(XA, PERM, ARS, RANK, P1, P2, CT1, CT2, Q1L, Q2L, QCT1, QCT2);
  // 6: scanB0
  k_scanB<<<1, 320, 0, stream>>>(CT1, CT2, QCT1, QCT2, OFF1, OFF2, QOF1, QOF2);
  // 7: combine0
  k_combine<<<4096, 256, 0, stream>>>(XA, AL, ARS, P1, P2, OFF1, OFF2, Q1L, Q2L, QOF1, QOF2, OT);
  // 8: aggr0
  k_aggr<<<2048, 256, 0, stream>>>(XA, OT, OFFS, ADJ, AGGR);
  // 9: gemm0 (+alar1 epilogue)
  k_gemmA<<<1024, 128, 0, stream>>>(AGGR, WT1, ww_b[0], XB, VP + 258, AL, AR_);
  // 10: rank1
  k_rank<<<256, 256, 0, stream>>>(AR_, RANK);
  // 11: perm1
  k_perm<<<32, 256, 0, stream>>>(RANK, AR_, PERM, ARS);
  // 12: scanA1 (RANK re-zero harmless)
  k_scanA<<<512, 256, 0, stream>>>(XB, PERM, ARS, RANK, P1, P2, CT1, CT2, Q1L, Q2L, QCT1, QCT2);
  // 13: scanB1
  k_scanB<<<1, 320, 0, stream>>>(CT1, CT2, QCT1, QCT2, OFF1, OFF2, QOF1, QOF2);
  // 14: combine1
  k_combine<<<4096, 256, 0, stream>>>(XB, AL, ARS, P1, P2, OFF1, OFF2, Q1L, Q2L, QOF1, QOF2, OT);
  // 15: aggr1
  k_aggr<<<2048, 256, 0, stream>>>(XB, OT, OFFS, ADJ, AGGR);
  // 16: gemm1 + lin -> FBF (bf16)
  k_gemmB<<<1024, 128, 0, stream>>>(AGGR, WT2, ww_b[1], WTL, lin_b, FBF);
  // 17: final
  k_final<<<dim3(64, 64), 256, 0, stream>>>((const unsigned short*)FBF, (float*)d_out);
}

// Round 13
// 299.042 us; speedup vs baseline: 4.6677x; 1.0073x over previous
//
#include <hip/hip_runtime.h>
#include <hip/hip_bf16.h>

#define NT 8192   // total nodes (2 graphs)
#define NN 4096   // nodes per graph
#define CD 128    // channels
#define NE 65536  // edges per graph

typedef __attribute__((ext_vector_type(8))) short bf16x8;
typedef __attribute__((ext_vector_type(16))) float f32x16;
typedef __attribute__((ext_vector_type(4))) float f32x4;

// ---------------- prep: concat + weight transposes + attention params + DEG zero ----------------
__global__ __launch_bounds__(256) void k_prep(
    const float* __restrict__ x1, const float* __restrict__ x2, float* __restrict__ X,
    const float* __restrict__ W1, const float* __restrict__ W2, const float* __restrict__ WL,
    float* __restrict__ WT1, float* __restrict__ WT2, float* __restrict__ WTL,
    const float* __restrict__ wlw0, const float* __restrict__ wlb0,
    const float* __restrict__ wrw0, const float* __restrict__ wrb0,
    const float* __restrict__ al0, const float* __restrict__ ar0,
    const float* __restrict__ wlw1, const float* __restrict__ wlb1,
    const float* __restrict__ wrw1, const float* __restrict__ wrb1,
    const float* __restrict__ al1, const float* __restrict__ ar1,
    float* __restrict__ VP, int* __restrict__ DEG) {
  int b = blockIdx.x, tid = threadIdx.x;
  int gid = b * 256 + tid;  // 0..131071
  {
    const f32x4* s1 = (const f32x4*)x1;
    const f32x4* s2 = (const f32x4*)x2;
    f32x4* d = (f32x4*)X;
    d[gid] = s1[gid];
    d[gid + NN * CD / 4] = s2[gid];
  }
  if (gid < 81920) {
    int idx = gid;
    if (idx < 32768) { int c = idx >> 8, k = idx & 255; WT1[k * 128 + c] = W1[idx]; }
    else if (idx < 65536) { int j = idx - 32768; int c = j >> 8, k = j & 255; WT2[k * 128 + c] = W2[j]; }
    else { int j = idx - 65536; int c = j >> 7, k = j & 127; WTL[k * 128 + c] = WL[j]; }
  }
  if ((b == 508 || b == 509) && tid < 128) {
    int L = b - 508;
    const float* wlw = L ? wlw1 : wlw0;
    const float* wlb = L ? wlb1 : wlb0;
    const float* wrw = L ? wrw1 : wrw0;
    const float* wrb = L ? wrb1 : wrb0;
    const float* alv = L ? al1 : al0;
    const float* arv = L ? ar1 : ar0;
    float* vp = VP + L * 258;
    int c = tid;
    float sl = 0.f, sr = 0.f;
    for (int h = 0; h < 128; ++h) {
      sl += wlw[h * 128 + c] * alv[h];
      sr += wrw[h * 128 + c] * arv[h];
    }
    vp[c] = sl;
    vp[128 + c] = sr;
    if (c < 2) {
      const float* bb = c ? wrb : wlb;
      const float* aa = c ? arv : alv;
      float s = 0.f;
      for (int h = 0; h < 128; ++h) s += bb[h] * aa[h];
      vp[256 + c] = s;
    }
  }
  if (gid < 2 * NN) DEG[gid] = 0;
}

// ---------------- shared bodies ----------------
__device__ inline void alar_row(const float* __restrict__ X, const float* __restrict__ VP,
                                float* __restrict__ AL, float* __restrict__ AR,
                                int row, int lane) {
  float x0 = X[row * 128 + lane], x1 = X[row * 128 + 64 + lane];
  float sl = x0 * VP[lane] + x1 * VP[64 + lane];
  float sr = x0 * VP[128 + lane] + x1 * VP[192 + lane];
  #pragma unroll
  for (int m = 1; m < 64; m <<= 1) {
    sl += __shfl_xor(sl, m, 64);
    sr += __shfl_xor(sr, m, 64);
  }
  if (lane == 0) { AL[row] = sl + VP[256]; AR[row] = sr + VP[257]; }
}

__device__ void rank_body(int rb, int tid, const float* __restrict__ AR,
                          int* __restrict__ RANK) {
  __shared__ float tile[1024];
  int jb = rb & 31, tb = rb >> 5;
  int base = tb * 1024;
  for (int t = tid; t < 1024; t += 256) tile[t] = AR[base + t];
  __syncthreads();
  int j = jb * 256 + tid;
  float aj = AR[j];
  int cnt = 0;
  #pragma unroll 8
  for (int u = 0; u < 1024; ++u) {
    float a2 = tile[u];
    cnt += (a2 < aj || (a2 == aj && (base + u) < j)) ? 1 : 0;
  }
  atomicAdd(&RANK[j], cnt);
}

__device__ void scanoff_body(int g, int tid, const int* __restrict__ DEG,
                             int* __restrict__ OFFS, int* __restrict__ CURS) {
  __shared__ int part[256];
  int loc[16];
  int s = 0;
  #pragma unroll
  for (int i = 0; i < 16; ++i) { loc[i] = s; s += DEG[g * NN + tid * 16 + i]; }
  part[tid] = s;
  __syncthreads();
  for (int d = 1; d < 256; d <<= 1) {
    int v = part[tid];
    int o = (tid >= d) ? part[tid - d] : 0;
    __syncthreads();
    part[tid] = v + o;
    __syncthreads();
  }
  int excl = tid ? part[tid - 1] : 0;
  #pragma unroll
  for (int i = 0; i < 16; ++i) {
    int o = excl + loc[i];
    OFFS[g * (NN + 1) + tid * 16 + i] = o;
    CURS[g * NN + tid * 16 + i] = o;
  }
  if (tid == 255) OFFS[g * (NN + 1) + NN] = part[255];
}

// ---------------- s2: deg atomics || alar0 (+RANK zero) ----------------
__global__ __launch_bounds__(256) void k_s2(
    const int* __restrict__ EI1, const int* __restrict__ EI2, int* __restrict__ DEG,
    const float* __restrict__ X, const float* __restrict__ VP0,
    float* __restrict__ AL, float* __restrict__ AR, int* __restrict__ RANK) {
  int b = blockIdx.x, tid = threadIdx.x;
  if (b < 512) {
    int gid = b * 256 + tid;
    int g = gid >> 16, e = gid & 65535;
    const int* src = g ? EI2 : EI1;
    atomicAdd(&DEG[g * NN + src[e]], 1);
  } else {
    int bb = b - 512;
    if (bb < 32) RANK[bb * 256 + tid] = 0;
    alar_row(X, VP0, AL, AR, bb * 4 + (tid >> 6), tid & 63);
  }
}

// ---------------- s3: scanoff || rank0 ----------------
__global__ __launch_bounds__(256) void k_s3(
    const int* __restrict__ DEG, int* __restrict__ OFFS, int* __restrict__ CURS,
    const float* __restrict__ AR, int* __restrict__ RANK) {
  int b = blockIdx.x, tid = threadIdx.x;
  if (b < 2) scanoff_body(b, tid, DEG, OFFS, CURS);
  else rank_body(b - 2, tid, AR, RANK);
}

// ---------------- s4: fill || perm0 ----------------
__global__ __launch_bounds__(256) void k_s4(
    const int* __restrict__ EI1, const int* __restrict__ EI2,
    int* __restrict__ CURS, int* __restrict__ ADJ,
    const int* __restrict__ RANK, const float* __restrict__ AR,
    int* __restrict__ PERM, float* __restrict__ ARS) {
  int b = blockIdx.x, tid = threadIdx.x;
  if (b < 512) {
    int gid = b * 256 + tid;
    int g = gid >> 16, e = gid & 65535;
    const int* ei = g ? EI2 : EI1;
    int s = ei[e], d = ei[NE + e];
    int pos = atomicAdd(&CURS[g * NN + s], 1);
    ADJ[g * NE + pos] = d;
  } else {
    int j = (b - 512) * 256 + tid;
    int r = RANK[j];
    PERM[r] = j;
    ARS[r] = AR[j];
  }
}

// plain rank (layer 1) and perm (layer 1)
__global__ void k_rank(const float* __restrict__ AR, int* __restrict__ RANK) {
  rank_body(blockIdx.x, threadIdx.x, AR, RANK);
}
__global__ void k_perm(const int* __restrict__ RANK, const float* __restrict__ AR,
                       int* __restrict__ PERM, float* __restrict__ ARS) {
  int j = blockIdx.x * 256 + threadIdx.x;
  int r = RANK[j];
  PERM[r] = j;
  ARS[r] = AR[j];
}

// hierarchical prefix sums, 4-way t-split (512 blocks); blocks<32 zero RANK for next rank pass
__global__ __launch_bounds__(256) void k_scanA(
    const float* __restrict__ X, const int* __restrict__ PERM,
    const float* __restrict__ ARS, int* __restrict__ RANK,
    float* __restrict__ P1, float* __restrict__ P2,
    float* __restrict__ CT1, float* __restrict__ CT2,
    float* __restrict__ Q1L, float* __restrict__ Q2L,
    float* __restrict__ QCT1, float* __restrict__ QCT2) {
  __shared__ int pc[64];
  __shared__ float w[2][64];
  __shared__ float part[2][4][32];
  __shared__ float qpart[2][4];
  int b = blockIdx.x;
  if (b < 32) RANK[b * 256 + threadIdx.x] = 0;
  int chunk = b >> 2, sub = b & 3;
  int tid = threadIdx.x;
  int a = tid >> 7;
  int g = (tid >> 5) & 3;
  int cl = tid & 31;
  int c = sub * 32 + cl;
  if (tid < 64) {
    int r = chunk * 64 + tid;
    pc[tid] = PERM[r];
    float ar = ARS[r];
    w[0][tid] = __expf(ar);
    w[1][tid] = __expf(0.2f * ar);
  }
  __syncthreads();
  int t0 = g * 16;
  float loc[16];
  float acc = 0.f;
  #pragma unroll 4
  for (int t = 0; t < 16; ++t) {
    acc += w[a][t0 + t] * X[pc[t0 + t] * 128 + c];
    loc[t] = acc;
  }
  part[a][g][cl] = acc;
  float qloc[16];
  float qacc = 0.f;
  bool doQ = (sub == 0 && cl == 0);
  if (doQ) {
    for (int t = 0; t < 16; ++t) { qacc += w[a][t0 + t]; qloc[t] = qacc; }
    qpart[a][g] = qacc;
  }
  __syncthreads();
  float off = (g > 0 ? part[a][0][cl] : 0.f) + (g > 1 ? part[a][1][cl] : 0.f) +
              (g > 2 ? part[a][2][cl] : 0.f);
  float* P = a ? P2 : P1;
  #pragma unroll 4
  for (int t = 0; t < 16; ++t) P[(chunk * 64 + t0 + t) * 128 + c] = loc[t] + off;
  if (g == 3) (a ? CT2 : CT1)[chunk * 128 + c] = off + acc;
  if (doQ) {
    float qoff = (g > 0 ? qpart[a][0] : 0.f) + (g > 1 ? qpart[a][1] : 0.f) +
                 (g > 2 ? qpart[a][2] : 0.f);
    float* Q = a ? Q2L : Q1L;
    for (int t = 0; t < 16; ++t) Q[chunk * 64 + t0 + t] = qloc[t] + qoff;
    if (g == 3) (a ? QCT2 : QCT1)[chunk] = qoff + qacc;
  }
}

__global__ __launch_bounds__(320) void k_scanB(
    const float* __restrict__ CT1, const float* __restrict__ CT2,
    const float* __restrict__ QCT1, const float* __restrict__ QCT2,
    float* __restrict__ OFF1, float* __restrict__ OFF2,
    float* __restrict__ QOF1, float* __restrict__ QOF2) {
  int tid = threadIdx.x;
  if (tid < 128) {
    float acc = 0.f;
    #pragma unroll 8
    for (int ch = 0; ch < 128; ++ch) { acc += CT1[ch * 128 + tid]; OFF1[ch * 128 + tid] = acc; }
  } else if (tid < 256) {
    int c = tid - 128;
    float acc = 0.f;
    #pragma unroll 8
    for (int ch = 0; ch < 128; ++ch) { acc += CT2[ch * 128 + c]; OFF2[ch * 128 + c] = acc; }
  } else if (tid == 256) {
    float acc = 0.f;
    for (int ch = 0; ch < 128; ++ch) { acc += QCT1[ch]; QOF1[ch] = acc; }
  } else if (tid == 257) {
    float acc = 0.f;
    for (int ch = 0; ch < 128; ++ch) { acc += QCT2[ch]; QOF2[ch] = acc; }
  }
}

// ot[i] = x[i] - (A1*suffix1 + A2*prefix2)/(A1*qsuf1 + A2*qpre2)
__global__ void k_combine(const float* __restrict__ X, const float* __restrict__ AL,
                          const float* __restrict__ ARS,
                          const float* __restrict__ P1, const float* __restrict__ P2,
                          const float* __restrict__ OFF1, const float* __restrict__ OFF2,
                          const float* __restrict__ Q1L, const float* __restrict__ Q2L,
                          const float* __restrict__ QOF1, const float* __restrict__ QOF2,
                          float* __restrict__ OT) {
  int row = blockIdx.x * 2 + (threadIdx.x >> 7);
  int c = threadIdx.x & 127;
  float ali = AL[row];
  float A1 = __expf(ali), A2 = __expf(0.2f * ali);
  float xv = -ali;
  int lo = 0, hi = NT;
  while (lo < hi) {
    int mid = (lo + hi) >> 1;
    if (ARS[mid] <= xv) lo = mid + 1; else hi = mid;
  }
  int b = lo - 1;
  float p1 = 0.f, p2 = 0.f, q1 = 0.f, q2 = 0.f;
  if (b >= 0) {
    int ch = b >> 6;
    p1 = P1[b * 128 + c] + (ch ? OFF1[(ch - 1) * 128 + c] : 0.f);
    p2 = P2[b * 128 + c] + (ch ? OFF2[(ch - 1) * 128 + c] : 0.f);
    q1 = Q1L[b] + (ch ? QOF1[ch - 1] : 0.f);
    q2 = Q2L[b] + (ch ? QOF2[ch - 1] : 0.f);
  }
  float T1 = OFF1[127 * 128 + c];
  float QT1 = QOF1[127];
  float num = A1 * (T1 - p1) + A2 * p2;
  float den = A1 * (QT1 - q1) + A2 * q2;
  OT[row * 128 + c] = X[row * 128 + c] - num / den;
}

// ---------------- fused: CSR-mean gather + relu + update GEMM (+ alar or lin epilogue) ----------------
__global__ __launch_bounds__(256) void k_ag(
    const float* __restrict__ X, const float* __restrict__ OT,
    const int* __restrict__ OFFS, const int* __restrict__ ADJ,
    const float* __restrict__ WT, const float* __restrict__ WB, float* __restrict__ XN,
    int mode,  // 0: + alar(next layer) ; 1: + lin -> FBF
    const float* __restrict__ VP1, float* __restrict__ AL, float* __restrict__ AR,
    const float* __restrict__ WTL, const float* __restrict__ LINB,
    __hip_bfloat16* __restrict__ FBF) {
  __shared__ float sA[8 * 256];  // 8 KB
  __shared__ float sB[8 * 128];  // 4 KB
  int b = blockIdx.x, tid = threadIdx.x;
  int lane = tid & 63, wv = tid >> 6, c4 = lane & 31;
  // gather phase: 2 nodes per wave
  {
    int beg[2], end[2];
    const f32x4* srcp[2];
    const int* adjp[2];
    f32x4 acc[2];
    #pragma unroll
    for (int k = 0; k < 2; ++k) {
      int node = b * 8 + wv * 2 + k;
      int g = node >> 12, n = node & (NN - 1);
      beg[k] = OFFS[g * (NN + 1) + n];
      end[k] = OFFS[g * (NN + 1) + n + 1];
      srcp[k] = (const f32x4*)((lane < 32 ? X : OT) + (size_t)g * NN * CD);
      adjp[k] = ADJ + g * NE;
      acc[k] = srcp[k][n * 32 + c4];
    }
    int maxd = max(end[0] - beg[0], end[1] - beg[1]);
    for (int s = 0; s < maxd; ++s) {
      #pragma unroll
      for (int k = 0; k < 2; ++k) {
        if (beg[k] + s < end[k]) acc[k] += srcp[k][adjp[k][beg[k] + s] * 32 + c4];
      }
    }
    #pragma unroll
    for (int k = 0; k < 2; ++k) {
      f32x4 r = acc[k] / (float)(end[k] - beg[k] + 1);
      #pragma unroll
      for (int q = 0; q < 4; ++q) r[q] = fmaxf(r[q], 0.f);
      *(f32x4*)&sA[(wv * 2 + k) * 256 + (lane < 32 ? c4 * 4 : 128 + c4 * 4)] = r;
    }
  }
  __syncthreads();
  // update GEMM: 8 rows x (256 -> 128)
  int c = tid & 127, half = tid >> 7;
  float accv[4];
  float bc = WB[c];
  #pragma unroll
  for (int i = 0; i < 4; ++i) accv[i] = bc;
  for (int k4 = 0; k4 < 64; ++k4) {
    float w0 = WT[(k4 * 4 + 0) * 128 + c];
    float w1v = WT[(k4 * 4 + 1) * 128 + c];
    float w2v = WT[(k4 * 4 + 2) * 128 + c];
    float w3 = WT[(k4 * 4 + 3) * 128 + c];
    #pragma unroll
    for (int i = 0; i < 4; ++i) {
      f32x4 av = *(const f32x4*)&sA[(half * 4 + i) * 256 + k4 * 4];
      accv[i] += av[0] * w0 + av[1] * w1v + av[2] * w2v + av[3] * w3;
    }
  }
  #pragma unroll
  for (int i = 0; i < 4; ++i) {
    sB[(half * 4 + i) * 128 + c] = accv[i];
    if (mode == 0) XN[(size_t)(b * 8 + half * 4 + i) * 128 + c] = accv[i];
  }
  __syncthreads();
  if (mode == 0) {
    // next-layer a_l/a_r from LDS rows (4 waves x 2 rows)
    #pragma unroll
    for (int k = 0; k < 2; ++k) {
      int lr = wv * 2 + k;
      float x0 = sB[lr * 128 + lane], x1 = sB[lr * 128 + 64 + lane];
      float sl = x0 * VP1[lane] + x1 * VP1[64 + lane];
      float sr = x0 * VP1[128 + lane] + x1 * VP1[192 + lane];
      #pragma unroll
      for (int m = 1; m < 64; m <<= 1) {
        sl += __shfl_xor(sl, m, 64);
        sr += __shfl_xor(sr, m, 64);
      }
      if (lane == 0) { AL[b * 8 + lr] = sl + VP1[256]; AR[b * 8 + lr] = sr + VP1[257]; }
    }
  } else {
    // lin GEMM: 8 rows x (128 -> 128), bf16 out
    float acl[4];
    float lb = LINB[c];
    #pragma unroll
    for (int i = 0; i < 4; ++i) acl[i] = lb;
    for (int k4 = 0; k4 < 32; ++k4) {
      float w0 = WTL[(k4 * 4 + 0) * 128 + c];
      float w1v = WTL[(k4 * 4 + 1) * 128 + c];
      float w2v = WTL[(k4 * 4 + 2) * 128 + c];
      float w3 = WTL[(k4 * 4 + 3) * 128 + c];
      #pragma unroll
      for (int i = 0; i < 4; ++i) {
        f32x4 av = *(const f32x4*)&sB[(half * 4 + i) * 128 + k4 * 4];
        acl[i] += av[0] * w0 + av[1] * w1v + av[2] * w2v + av[3] * w3;
      }
    }
    #pragma unroll
    for (int i = 0; i < 4; ++i)
      FBF[(size_t)(b * 8 + half * 4 + i) * 128 + c] = __float2bfloat16(acl[i]);
  }
}

// ---------------- final: out = sigmoid(F F^T), F bf16 8192x128 ----------------
__device__ inline f32x16 zero16() {
  f32x16 v;
  #pragma unroll
  for (int i = 0; i < 16; ++i) v[i] = 0.f;
  return v;
}

__device__ inline float sigf(float v) {
  return __builtin_amdgcn_rcpf(1.f + __expf(-v));
}

__global__ __launch_bounds__(256) void k_final(const unsigned short* __restrict__ F,
                                               float* __restrict__ out) {
  __shared__ __align__(16) char smem[65536];
  unsigned short* AT = (unsigned short*)smem;
  unsigned short* BT = AT + 16384;
  int cb = blockIdx.x, rb = blockIdx.y;
  int tid = threadIdx.x;
  // stage two 128x128 bf16 tiles, XOR-swizzled rows (bank-conflict fix)
  #pragma unroll
  for (int q = 0; q < 8; ++q) {
    int idx = q * 256 + tid;
    int r = idx >> 4, ck = idx & 15;
    unsigned off = (unsigned)((r * 256 + ck * 16) ^ ((r & 7) << 4));
    uint4 va = *(const uint4*)(F + (size_t)(rb * 128 + r) * 128 + ck * 8);
    *(uint4*)((char*)AT + off) = va;
    uint4 vb = *(const uint4*)(F + (size_t)(cb * 128 + r) * 128 + ck * 8);
    *(uint4*)((char*)BT + off) = vb;
  }
  __syncthreads();
  int lane = tid & 63, w = tid >> 6;
  int wr = w >> 1, wc = w & 1;
  int l31 = lane & 31, kh = lane >> 5;
  int xorm = (l31 & 7) << 4;
  int rowA0 = wr * 64 + l31, rowA1 = rowA0 + 32;
  int rowB0 = wc * 64 + l31, rowB1 = rowB0 + 32;
  f32x16 a00 = zero16(), a01 = zero16(), a10 = zero16(), a11 = zero16();
  #pragma unroll
  for (int ks = 0; ks < 8; ++ks) {
    int kb = ks * 32 + kh * 16;
    bf16x8 av0 = *(const bf16x8*)((const char*)AT + ((rowA0 * 256 + kb) ^ xorm));
    bf16x8 av1 = *(const bf16x8*)((const char*)AT + ((rowA1 * 256 + kb) ^ xorm));
    bf16x8 bv0 = *(const bf16x8*)((const char*)BT + ((rowB0 * 256 + kb) ^ xorm));
    bf16x8 bv1 = *(const bf16x8*)((const char*)BT + ((rowB1 * 256 + kb) ^ xorm));
    a00 = __builtin_amdgcn_mfma_f32_32x32x16_bf16(av0, bv0, a00, 0, 0, 0);
    a01 = __builtin_amdgcn_mfma_f32_32x32x16_bf16(av0, bv1, a01, 0, 0, 0);
    a10 = __builtin_amdgcn_mfma_f32_32x32x16_bf16(av1, bv0, a10, 0, 0, 0);
    a11 = __builtin_amdgcn_mfma_f32_32x32x16_bf16(av1, bv1, a11, 0, 0, 0);
  }
  __syncthreads();  // all AT/BT reads complete; reuse LDS as f32 staging
  // each wave owns a 64x64 f32 tile (16 KB): rows wr*64.., cols wc*64..
  float* lw = (float*)smem + w * 4096;
  #pragma unroll
  for (int r = 0; r < 16; ++r) {
    int rl = (r & 3) + 8 * (r >> 2) + 4 * kh;  // 0..31
    lw[rl * 64 + l31] = sigf(a00[r]);
    lw[rl * 64 + l31 + 32] = sigf(a01[r]);
    lw[(rl + 32) * 64 + l31] = sigf(a10[r]);
    lw[(rl + 32) * 64 + l31 + 32] = sigf(a11[r]);
  }
  // wave-local data: no barrier needed (compiler orders ds ops via lgkmcnt)
  int grb = rb * 128 + wr * 64, gcb = cb * 128 + wc * 64;
  #pragma unroll
  for (int j = 0; j < 16; ++j) {
    int row = j * 4 + (lane >> 4);
    int c4 = (lane & 15) * 4;
    f32x4 v = *(const f32x4*)&lw[row * 64 + c4];
    *(f32x4*)&out[(size_t)(grb + row) * 8192 + gcb + c4] = v;
  }
}

// ---------------- host ----------------
extern "C" void kernel_launch(void* const* d_in, const int* in_sizes, int n_in,
                              void* d_out, int out_size, void* d_ws, size_t ws_size,
                              hipStream_t stream) {
  (void)in_sizes; (void)n_in; (void)out_size; (void)ws_size;
  const float* x1 = (const float*)d_in[0];
  const float* x2 = (const float*)d_in[1];
  const int* ei1 = (const int*)d_in[2];
  const int* ei2 = (const int*)d_in[3];
  const float* wl_w[2] = {(const float*)d_in[4], (const float*)d_in[10]};
  const float* wl_b[2] = {(const float*)d_in[5], (const float*)d_in[11]};
  const float* wr_w[2] = {(const float*)d_in[6], (const float*)d_in[12]};
  const float* wr_b[2] = {(const float*)d_in[7], (const float*)d_in[13]};
  const float* alv[2] = {(const float*)d_in[8], (const float*)d_in[14]};
  const float* arv[2] = {(const float*)d_in[9], (const float*)d_in[15]};
  const float* ww_w[2] = {(const float*)d_in[16], (const float*)d_in[18]};
  const float* ww_b[2] = {(const float*)d_in[17], (const float*)d_in[19]};
  const float* lin_w = (const float*)d_in[20];
  const float* lin_b = (const float*)d_in[21];

  char* wp = (char*)d_ws;
  auto alloc = [&](size_t b) -> char* {
    char* p = wp;
    wp += (b + 255) & ~(size_t)255;
    return p;
  };
  float* XA = (float*)alloc((size_t)NT * CD * 4);
  float* XB = (float*)alloc((size_t)NT * CD * 4);
  float* OT = (float*)alloc((size_t)NT * CD * 4);
  float* P1 = (float*)alloc((size_t)NT * CD * 4);
  float* P2 = (float*)alloc((size_t)NT * CD * 4);
  __hip_bfloat16* FBF = (__hip_bfloat16*)alloc((size_t)NT * CD * 2);
  float* CT1 = (float*)alloc(128 * 128 * 4);
  float* CT2 = (float*)alloc(128 * 128 * 4);
  float* OFF1 = (float*)alloc(128 * 128 * 4);
  float* OFF2 = (float*)alloc(128 * 128 * 4);
  float* AL = (float*)alloc(NT * 4);
  float* AR_ = (float*)alloc(NT * 4);
  float* ARS = (float*)alloc(NT * 4);
  float* Q1L = (float*)alloc(NT * 4);
  float* Q2L = (float*)alloc(NT * 4);
  float* QCT1 = (float*)alloc(128 * 4);
  float* QCT2 = (float*)alloc(128 * 4);
  float* QOF1 = (float*)alloc(128 * 4);
  float* QOF2 = (float*)alloc(128 * 4);
  float* VP = (float*)alloc(2 * 258 * 4);
  float* WT1 = (float*)alloc(256 * 128 * 4);
  float* WT2 = (float*)alloc(256 * 128 * 4);
  float* WTL = (float*)alloc(128 * 128 * 4);
  int* RANK = (int*)alloc(NT * 4);
  int* PERM = (int*)alloc(NT * 4);
  int* DEG = (int*)alloc(2 * NN * 4);
  int* OFFS = (int*)alloc(2 * (NN + 1) * 4);
  int* CURS = (int*)alloc(2 * NN * 4);
  int* ADJ = (int*)alloc(2 * NE * 4);

  // 1: prep (concat + transposes + params + DEG zero)
  k_prep<<<512, 256, 0, stream>>>(x1, x2, XA, ww_w[0], ww_w[1], lin_w, WT1, WT2, WTL,
                                  wl_w[0], wl_b[0], wr_w[0], wr_b[0], alv[0], arv[0],
                                  wl_w[1], wl_b[1], wr_w[1], wr_b[1], alv[1], arv[1],
                                  VP, DEG);
  // 2: deg || alar0 (+RANK zero)
  k_s2<<<2560, 256, 0, stream>>>(ei1, ei2, DEG, XA, VP, AL, AR_, RANK);
  // 3: scanoff || rank0
  k_s3<<<258, 256, 0, stream>>>(DEG, OFFS, CURS, AR_, RANK);
  // 4: fill || perm0
  k_s4<<<544, 256, 0, stream>>>(ei1, ei2, CURS, ADJ, RANK, AR_, PERM, ARS);
  // 5: scanA0 (+RANK zero for layer1)
  k_scanA<<<512, 256, 0, stream>>>(XA, PERM, ARS, RANK, P1, P2, CT1, CT2, Q1L, Q2L, QCT1, QCT2);
  // 6: scanB0
  k_scanB<<<1, 320, 0, stream>>>(CT1, CT2, QCT1, QCT2, OFF1, OFF2, QOF1, QOF2);
  // 7: combine0
  k_combine<<<4096, 256, 0, stream>>>(XA, AL, ARS, P1, P2, OFF1, OFF2, Q1L, Q2L, QOF1, QOF2, OT);
  // 8: aggr+gemm0 (+alar1 epilogue)
  k_ag<<<1024, 256, 0, stream>>>(XA, OT, OFFS, ADJ, WT1, ww_b[0], XB,
                                 0, VP + 258, AL, AR_, WTL, lin_b, FBF);
  // 9: rank1
  k_rank<<<256, 256, 0, stream>>>(AR_, RANK);
  // 10: perm1
  k_perm<<<32, 256, 0, stream>>>(RANK, AR_, PERM, ARS);
  // 11: scanA1 (RANK re-zero harmless)
  k_scanA<<<512, 256, 0, stream>>>(XB, PERM, ARS, RANK, P1, P2, CT1, CT2, Q1L, Q2L, QCT1, QCT2);
  // 12: scanB1
  k_scanB<<<1, 320, 0, stream>>>(CT1, CT2, QCT1, QCT2, OFF1, OFF2, QOF1, QOF2);
  // 13: combine1
  k_combine<<<4096, 256, 0, stream>>>(XB, AL, ARS, P1, P2, OFF1, OFF2, Q1L, Q2L, QOF1, QOF2, OT);
  // 14: aggr+gemm1 (+lin -> FBF)
  k_ag<<<1024, 256, 0, stream>>>(XB, OT, OFFS, ADJ, WT2, ww_b[1], XB,
                                 1, VP, AL, AR_, WTL, lin_b, FBF);
  // 15: final
  k_final<<<dim3(64, 64), 256, 0, stream>>>((const unsigned short*)FBF, (float*)d_out);
}